// Round 2
// baseline (497.869 us; speedup 1.0000x reference)
//
#include <hip/hip_runtime.h>
#include <hip/hip_fp16.h>
#include <cmath>

#define G_NUM 128
#define NPTS  128
#define FDIM  128
#define KNNK  24
#define NTOT  (G_NUM*NPTS)   // 16384

__device__ __forceinline__ float eluf(float x){ return x > 0.0f ? x : expm1f(x); }

// ---------------------------------------------------------------------------
// prep: Wcat[l][k][0:128] = Wtop-Wbot ; Wcat[l][k][128:256] = Wbot ; bias256
// ---------------------------------------------------------------------------
__global__ void prep_kernel(const float* __restrict__ w1, const float* __restrict__ w2,
                            const float* __restrict__ w3,
                            const float* __restrict__ b1, const float* __restrict__ b2,
                            const float* __restrict__ b3,
                            float* __restrict__ wcat, float* __restrict__ bias)
{
    int e = blockIdx.x * 256 + threadIdx.x;
    if (e < 3 * 128 * 128) {
        int l = e >> 14;
        int r = e & 16383;
        int k = r >> 7;
        int h = r & 127;
        const float* w = (l == 0) ? w1 : ((l == 1) ? w2 : w3);
        float wt = w[k * 128 + h];
        float wb = w[(128 + k) * 128 + h];
        float* wc = wcat + l * 128 * 256;
        wc[k * 256 + h]       = wt - wb;
        wc[k * 256 + 128 + h] = wb;
    }
    if (e < 3 * 256) {
        int l = e >> 8, j = e & 255;
        const float* b = (l == 0) ? b1 : ((l == 1) ? b2 : b3);
        bias[l * 256 + j] = (j < 128) ? b[j] : 0.0f;
    }
}

// ---------------------------------------------------------------------------
// GEMM v2: C = act(A[M x KD] @ B[KD x N] + bias). Tile TM x 128, 256 threads,
// 8x8 (or 4x8) microtile with rows/cols strided by 16 -> all-scalar LDS reads,
// conflict-free (odd pitch KD+1 / 129). Epilogue restaged through LDS
// (pitch 132: bank-injective writes) for coalesced float4 global stores.
// grid.y selects output buffer: y==0 -> C0 (cols 0..127), y==1 -> C1 (128..255).
// ---------------------------------------------------------------------------
template<int KD, int TM, int DOELU>
__global__ __launch_bounds__(256) void gemm2(const float* __restrict__ A, int lda,
                                             const float* __restrict__ B, int ldb,
                                             const float* __restrict__ bias,
                                             float* __restrict__ C0,
                                             float* __restrict__ C1)
{
    extern __shared__ float sm[];
    float* As = sm;                   // TM x (KD+1)
    float* Bs = sm + TM * (KD + 1);   // KD x 129
    const int tid = threadIdx.x;
    const int m0 = blockIdx.x * TM;
    const int n0 = blockIdx.y * 128;
    float* C = blockIdx.y ? C1 : C0;
    const float* bg = bias + n0;

    constexpr int NF4 = KD / 4;
    for (int e = tid; e < TM * NF4; e += 256) {
        int q = e % NF4, m = e / NF4;
        float4 v = *reinterpret_cast<const float4*>(&A[(size_t)(m0 + m) * lda + 4 * q]);
        float* dst = &As[m * (KD + 1) + 4 * q];
        dst[0] = v.x; dst[1] = v.y; dst[2] = v.z; dst[3] = v.w;
    }
    for (int e = tid; e < KD * 32; e += 256) {
        int q = e & 31, k = e >> 5;
        float4 v = *reinterpret_cast<const float4*>(&B[(size_t)k * ldb + n0 + 4 * q]);
        float* dst = &Bs[k * 129 + 4 * q];
        dst[0] = v.x; dst[1] = v.y; dst[2] = v.z; dst[3] = v.w;
    }
    __syncthreads();

    const int tml = tid & 15;      // row sub-index (stride 16)
    const int tnh = tid >> 4;      // col sub-index (stride 16), 0..15
    constexpr int NR = TM / 16;
    float acc[NR][8] = {};
    #pragma unroll 4
    for (int k = 0; k < KD; ++k) {
        float av[NR], bv[8];
        #pragma unroll
        for (int s = 0; s < NR; ++s) av[s] = As[(tml + 16 * s) * (KD + 1) + k];
        #pragma unroll
        for (int u = 0; u < 8; ++u) bv[u] = Bs[k * 129 + tnh + 16 * u];
        #pragma unroll
        for (int s = 0; s < NR; ++s)
            #pragma unroll
            for (int u = 0; u < 8; ++u) acc[s][u] += av[s] * bv[u];
    }
    __syncthreads();
    float* Ce = sm;  // TM x 132, aliases As/Bs (dead)
    #pragma unroll
    for (int s = 0; s < NR; ++s)
        #pragma unroll
        for (int u = 0; u < 8; ++u)
            Ce[(tml + 16 * s) * 132 + tnh + 16 * u] = acc[s][u];
    __syncthreads();
    for (int e = tid; e < TM * 32; e += 256) {
        int q = e & 31, m = e >> 5;
        float4 v = *reinterpret_cast<const float4*>(&Ce[m * 132 + 4 * q]);
        float4 b4 = *reinterpret_cast<const float4*>(&bg[4 * q]);
        v.x += b4.x; v.y += b4.y; v.z += b4.z; v.w += b4.w;
        if (DOELU) { v.x = eluf(v.x); v.y = eluf(v.y); v.z = eluf(v.z); v.w = eluf(v.w); }
        *reinterpret_cast<float4*>(&C[(size_t)(m0 + m) * 128 + 4 * q]) = v;
    }
}

// ---------------------------------------------------------------------------
// edge: 2 blocks per graph (rows r0..r0+63). Stages X (128x129), computes d2
// (4x8 microtile, strided, conflict-free), stages c as f16x2, then per wave:
// radix-select top-24 (sortable-uint bit loop, ballot counts, exact top_k tie
// rule) fused with set-max combine and elu(a + maxc) in-place into hio.
// ---------------------------------------------------------------------------
__global__ __launch_bounds__(256) void edge_kernel(const float* __restrict__ hin,
                                                   const float* __restrict__ cc,
                                                   float* __restrict__ hio)
{
    extern __shared__ float sm[];
    float* Xs = sm;                      // [128][129]
    float* D  = sm + 16512;              // [64][132]
    float* Sq = sm + 16512 + 8448;       // [128]
    unsigned int* Cc = (unsigned int*)sm; // [128][64] f16x2, overlays Xs after d2

    const int g = blockIdx.x >> 1, half = blockIdx.x & 1;
    const int r0 = half * 64;
    const int tid = threadIdx.x;
    const float* hg = hin + (size_t)g * NPTS * FDIM;
    const float* cg = cc  + (size_t)g * NPTS * FDIM;
    float* og = hio + (size_t)g * NPTS * FDIM;

    for (int e = tid; e < 128 * 32; e += 256) {
        int q = e & 31, m = e >> 5;
        float4 v = *reinterpret_cast<const float4*>(&hg[m * 128 + 4 * q]);
        float* dst = &Xs[m * 129 + 4 * q];
        dst[0] = v.x; dst[1] = v.y; dst[2] = v.z; dst[3] = v.w;
    }
    __syncthreads();
    if (tid < 128) {
        float s = 0.f;
        #pragma unroll 8
        for (int k = 0; k < 128; ++k) { float v = Xs[tid * 129 + k]; s += v * v; }
        Sq[tid] = s;
    }
    __syncthreads();

    {   // d2: rows r0 + tml + 16s (s=0..3), cols tnh + 16u (u=0..7)
        const int tml = tid & 15, tnh = tid >> 4;
        float acc[4][8] = {};
        #pragma unroll 2
        for (int k = 0; k < 128; ++k) {
            float av[4], bv[8];
            #pragma unroll
            for (int s = 0; s < 4; ++s) av[s] = Xs[(r0 + tml + 16 * s) * 129 + k];
            #pragma unroll
            for (int u = 0; u < 8; ++u) bv[u] = Xs[(tnh + 16 * u) * 129 + k];
            #pragma unroll
            for (int s = 0; s < 4; ++s)
                #pragma unroll
                for (int u = 0; u < 8; ++u) acc[s][u] += av[s] * bv[u];
        }
        #pragma unroll
        for (int s = 0; s < 4; ++s) {
            float sqa = Sq[r0 + tml + 16 * s];
            #pragma unroll
            for (int u = 0; u < 8; ++u)
                D[(tml + 16 * s) * 132 + tnh + 16 * u] =
                    sqa + Sq[tnh + 16 * u] - 2.f * acc[s][u];
        }
    }
    __syncthreads();

    // stage c (all 128 rows) as packed f16x2 into the dead Xs region
    for (int e = tid; e < 128 * 32; e += 256) {
        int q = e & 31, j = e >> 5;
        float4 v = *reinterpret_cast<const float4*>(&cg[j * 128 + 4 * q]);
        unsigned int p0 = ((unsigned int)__half_as_ushort(__float2half(v.y)) << 16)
                        |  (unsigned int)__half_as_ushort(__float2half(v.x));
        unsigned int p1 = ((unsigned int)__half_as_ushort(__float2half(v.w)) << 16)
                        |  (unsigned int)__half_as_ushort(__float2half(v.z));
        Cc[j * 64 + 2 * q]     = p0;
        Cc[j * 64 + 2 * q + 1] = p1;
    }
    __syncthreads();

    // per wave: 16 rows. lane l holds cols {2l, 2l+1}.
    const int w = tid >> 6, l = tid & 63;
    const int lrEnd = w * 16 + 16;
    float2 dv = *reinterpret_cast<const float2*>(&D[(w * 16) * 132 + 2 * l]);
    for (int lr = w * 16; lr < lrEnd; ++lr) {
        float2 cur = dv;
        if (lr + 1 < lrEnd)
            dv = *reinterpret_cast<const float2*>(&D[(lr + 1) * 132 + 2 * l]);

        unsigned int ub0 = __float_as_uint(cur.x);
        unsigned int ub1 = __float_as_uint(cur.y);
        unsigned int u0 = (ub0 & 0x80000000u) ? ~ub0 : (ub0 | 0x80000000u);
        unsigned int u1 = (ub1 & 0x80000000u) ? ~ub1 : (ub1 | 0x80000000u);

        bool c0 = true, c1 = true, in0 = false, in1 = false;
        int need = KNNK;
        for (int b = 31; b >= 0; --b) {
            bool z0 = c0 && !((u0 >> b) & 1u);
            bool z1 = c1 && !((u1 >> b) & 1u);
            int cnt = __popcll(__ballot(z0)) + __popcll(__ballot(z1));
            if (cnt > need) { c0 = z0; c1 = z1; }
            else if (cnt == need) { in0 |= z0; in1 |= z1; need = 0; break; }
            else { in0 |= z0; in1 |= z1; need -= cnt;
                   c0 = c0 && !z0; c1 = c1 && !z1; }
        }
        if (need > 0) {  // exact-duplicate boundary values: take lowest col indices
            unsigned long long m0 = __ballot(c0), m1 = __ballot(c1);
            unsigned long long below = (1ull << l) - 1ull;
            int rk0 = __popcll(m0 & below) + __popcll(m1 & below);
            int rk1 = rk0 + (int)((m0 >> l) & 1ull);
            in0 = in0 || (c0 && rk0 < need);
            in1 = in1 || (c1 && rk1 < need);
        }
        unsigned long long s0 = __ballot(in0), s1 = __ballot(in1);

        // issue 'a' load early (global latency hidden under combine)
        float2 av = *reinterpret_cast<const float2*>(&og[(r0 + lr) * 128 + 2 * l]);

        float mc0 = -3.0e38f, mc1 = -3.0e38f;
        while (s0) {
            int p = __ffsll((unsigned long long)s0) - 1; s0 &= s0 - 1ull;
            unsigned int cw = Cc[(2 * p) * 64 + l];
            mc0 = fmaxf(mc0, __half2float(__ushort_as_half((unsigned short)(cw & 0xffffu))));
            mc1 = fmaxf(mc1, __half2float(__ushort_as_half((unsigned short)(cw >> 16))));
        }
        while (s1) {
            int p = __ffsll((unsigned long long)s1) - 1; s1 &= s1 - 1ull;
            unsigned int cw = Cc[(2 * p + 1) * 64 + l];
            mc0 = fmaxf(mc0, __half2float(__ushort_as_half((unsigned short)(cw & 0xffffu))));
            mc1 = fmaxf(mc1, __half2float(__ushort_as_half((unsigned short)(cw >> 16))));
        }
        float2 o;
        o.x = eluf(av.x + mc0);
        o.y = eluf(av.y + mc1);
        *reinterpret_cast<float2*>(&og[(r0 + lr) * 128 + 2 * l]) = o;
    }
}

// ---------------------------------------------------------------------------
// head: per-graph sum-pool (2-way split) + 128->64->32->32->6 MLP
// ---------------------------------------------------------------------------
__global__ __launch_bounds__(256) void head_kernel(const float* __restrict__ h,
        const float* __restrict__ w1, const float* __restrict__ b1,
        const float* __restrict__ w2, const float* __restrict__ b2,
        const float* __restrict__ w3, const float* __restrict__ b3,
        const float* __restrict__ w4, const float* __restrict__ b4,
        float* __restrict__ out)
{
    __shared__ float ps[2][128];
    __shared__ float pooled[128], s1[64], s2[32], s3[32];
    const int g = blockIdx.x, t = threadIdx.x;
    const float* hg = h + (size_t)g * NPTS * FDIM;
    const int f = t & 127, hp = t >> 7;
    float s = 0.0f;
    for (int p = 0; p < 64; ++p) s += hg[(hp * 64 + p) * 128 + f];
    ps[hp][f] = s;
    __syncthreads();
    if (t < 128) pooled[t] = ps[0][t] + ps[1][t];
    __syncthreads();
    if (t < 64) {
        float a = b1[t];
        #pragma unroll 8
        for (int k = 0; k < 128; ++k) a += pooled[k] * w1[k * 64 + t];
        s1[t] = eluf(a);
    }
    __syncthreads();
    if (t < 32) {
        float a = b2[t];
        #pragma unroll 8
        for (int k = 0; k < 64; ++k) a += s1[k] * w2[k * 32 + t];
        s2[t] = eluf(a);
    }
    __syncthreads();
    if (t < 32) {
        float a = b3[t];
        #pragma unroll 8
        for (int k = 0; k < 32; ++k) a += s2[k] * w3[k * 32 + t];
        s3[t] = eluf(a);
    }
    __syncthreads();
    if (t < 6) {
        float a = b4[t];
        #pragma unroll 8
        for (int k = 0; k < 32; ++k) a += s3[k] * w4[k * 6 + t];
        out[g * 6 + t] = a;
    }
}

__global__ void batch_kernel(const int* __restrict__ bpf, float* __restrict__ out)
{
    int i = blockIdx.x * 256 + threadIdx.x;
    if (i < NTOT) out[768 + i] = (float)bpf[i];
}

// ---------------------------------------------------------------------------
extern "C" void kernel_launch(void* const* d_in, const int* in_sizes, int n_in,
                              void* d_out, int out_size, void* d_ws, size_t ws_size,
                              hipStream_t stream)
{
    const float* x_pf   = (const float*)d_in[0];
    const float* enc_w1 = (const float*)d_in[1];
    const float* enc_b1 = (const float*)d_in[2];
    const float* enc_w2 = (const float*)d_in[3];
    const float* enc_b2 = (const float*)d_in[4];
    const float* c1w = (const float*)d_in[5];
    const float* c1b = (const float*)d_in[6];
    const float* c2w = (const float*)d_in[7];
    const float* c2b = (const float*)d_in[8];
    const float* c3w = (const float*)d_in[9];
    const float* c3b = (const float*)d_in[10];
    const float* o_w1 = (const float*)d_in[11];
    const float* o_b1 = (const float*)d_in[12];
    const float* o_w2 = (const float*)d_in[13];
    const float* o_b2 = (const float*)d_in[14];
    const float* o_w3 = (const float*)d_in[15];
    const float* o_b3 = (const float*)d_in[16];
    const float* o_w4 = (const float*)d_in[17];
    const float* o_b4 = (const float*)d_in[18];
    const int*   bpf  = (const int*)d_in[19];
    float* out = (float*)d_out;

    float* ws   = (float*)d_ws;
    float* h_a  = ws;                            // 16384*128
    float* h_b  = h_a + (size_t)NTOT * FDIM;     // 16384*128
    float* ac_c = h_b + (size_t)NTOT * FDIM;     // 16384*128 (c features)
    float* wcat = ac_c + (size_t)NTOT * FDIM;    // 3*128*256
    float* bias = wcat + 3 * 128 * 256;          // 3*256

    prep_kernel<<<192, 256, 0, stream>>>(c1w, c2w, c3w, c1b, c2b, c3b, wcat, bias);

    // LDS sizes (floats): max(As+Bs, TM*132)
    const size_t lds_e1 = (size_t)8448 * 4;                               // KD=16,TM=64
    const size_t lds_e2 = (size_t)(64 * 129 + 128 * 129) * 4;             // KD=128,TM=64
    const size_t lds_cv = (size_t)(128 * 129 + 128 * 129) * 4;            // KD=128,TM=128
    const size_t lds_edge = (size_t)(16512 + 8448 + 128) * 4;

    // encoder
    gemm2<16, 64, 1><<<dim3(NTOT / 64, 1), 256, lds_e1, stream>>>(
        x_pf, 16, enc_w1, 128, enc_b1, ac_c, nullptr);
    gemm2<128, 64, 1><<<dim3(NTOT / 64, 1), 256, lds_e2, stream>>>(
        ac_c, 128, enc_w2, 128, enc_b2, h_a, nullptr);

    float* hc = h_a;
    float* hn = h_b;
    for (int l = 0; l < 3; ++l) {
        // a -> hn (cols 0..127), c -> ac_c (cols 128..255)
        gemm2<128, 128, 0><<<dim3(NTOT / 128, 2), 256, lds_cv, stream>>>(
            hc, 128, wcat + (size_t)l * 128 * 256, 256, bias + l * 256, hn, ac_c);
        edge_kernel<<<2 * G_NUM, 256, lds_edge, stream>>>(hc, ac_c, hn);
        float* t = hc; hc = hn; hn = t;
    }

    head_kernel<<<G_NUM, 256, 0, stream>>>(hc, o_w1, o_b1, o_w2, o_b2, o_w3, o_b3,
                                           o_w4, o_b4, out);
    batch_kernel<<<64, 256, 0, stream>>>(bpf, out);
}

// Round 3
// 338.824 us; speedup vs baseline: 1.4694x; 1.4694x over previous
//
#include <hip/hip_runtime.h>
#include <hip/hip_fp16.h>
#include <cmath>

#define G_NUM 128
#define NPTS  128
#define FDIM  128
#define KNNK  24
#define NTOT  (G_NUM*NPTS)   // 16384

typedef short s8v __attribute__((ext_vector_type(8)));   // 8 bf16 (4 VGPRs)
typedef float f32x4 __attribute__((ext_vector_type(4))); // MFMA accumulator

__device__ __forceinline__ float eluf(float x){ return x > 0.0f ? x : expm1f(x); }

__device__ __forceinline__ unsigned short f2bf(float f) {
    unsigned int u = __float_as_uint(f);
    unsigned int r = (u + 0x7fffu + ((u >> 16) & 1u)) >> 16;   // RNE
    return (unsigned short)r;
}

// ---------------------------------------------------------------------------
// prep: wcatT[l][n][k] bf16 (n<128: Wtop-Wbot col, else Wbot col), enc2T[n][k]
// bf16, bias[l][256] f32 (c-half zero).
// ---------------------------------------------------------------------------
__global__ void prep_kernel(const float* __restrict__ w1, const float* __restrict__ w2,
                            const float* __restrict__ w3, const float* __restrict__ ew2,
                            const float* __restrict__ b1, const float* __restrict__ b2,
                            const float* __restrict__ b3,
                            unsigned short* __restrict__ wcatT,
                            unsigned short* __restrict__ enc2T,
                            float* __restrict__ bias)
{
    int e = blockIdx.x * 256 + threadIdx.x;
    if (e < 98304) {                       // 3 * 128k * 256n
        int l = e >> 15;
        int r = e & 32767;
        int k = r >> 8;                    // 0..127
        int n = r & 255;                   // 0..255 (coalesced reads over n)
        const float* w = (l == 0) ? w1 : ((l == 1) ? w2 : w3);
        float v = (n < 128) ? (w[k * 128 + n] - w[(128 + k) * 128 + n])
                            : w[(128 + k) * 128 + (n - 128)];
        wcatT[l * 32768 + n * 128 + k] = f2bf(v);
    } else if (e < 114688) {               // enc2T: 128k * 128n
        int i = e - 98304;
        int k = i >> 7, n = i & 127;
        enc2T[n * 128 + k] = f2bf(ew2[k * 128 + n]);
    } else if (e < 115456) {
        int j = e - 114688;
        int l = j >> 8, c = j & 255;
        const float* b = (l == 0) ? b1 : ((l == 1) ? b2 : b3);
        bias[l * 256 + c] = (c < 128) ? b[c] : 0.0f;
    }
}

// ---------------------------------------------------------------------------
// MFMA GEMM: C = act(A[M x 128] @ B + bias). BM=128, BN=128, K=128 one shot.
// A fp32 -> bf16 cvt during staging; B pre-transposed bf16 (Bt[n][k]).
// LDS 64KB (2 blocks/CU). XOR swizzle byte^=(row&15)<<4 on stage+frag reads.
// Frag layout: A/B lane l holds 8 contiguous k at k=(l>>4)*8 (one b128 read);
// C/D: col=lane&15, row=(lane>>4)*4+reg (m89-verified).
// ---------------------------------------------------------------------------
template<int DOELU>
__global__ __launch_bounds__(256) void gemmT(const float* __restrict__ A,
                                             const unsigned short* __restrict__ Bt,
                                             const float* __restrict__ bias,
                                             float* __restrict__ C0,
                                             float* __restrict__ C1)
{
    extern __shared__ char smc[];          // [0,32768) A bf16, [32768,65536) B bf16
    const int tid = threadIdx.x;
    const int m0 = blockIdx.x * 128;
    const unsigned short* Btg = Bt + (size_t)blockIdx.y * 16384;
    const float* bg = bias + blockIdx.y * 128;
    float* C = blockIdx.y ? C1 : C0;

    // stage A: 128 rows x 128 k fp32 -> bf16
    for (int e = tid; e < 4096; e += 256) {
        int m = e >> 5, q = e & 31;
        float4 v = *reinterpret_cast<const float4*>(&A[(size_t)(m0 + m) * 128 + 4 * q]);
        ushort4 p;
        p.x = f2bf(v.x); p.y = f2bf(v.y); p.z = f2bf(v.z); p.w = f2bf(v.w);
        int byte = (m * 256 + q * 8) ^ ((m & 15) << 4);
        *reinterpret_cast<ushort4*>(smc + byte) = p;
    }
    // stage B: linear bf16 copy (row n = 256B)
    for (int e = tid; e < 2048; e += 256) {
        int n = e >> 4, q = e & 15;
        uint4 v = *reinterpret_cast<const uint4*>(Btg + n * 128 + q * 8);
        int byte = (n * 256 + q * 16) ^ ((n & 15) << 4);
        *reinterpret_cast<uint4*>(smc + 32768 + byte) = v;
    }
    __syncthreads();

    const int l = tid & 63, w = tid >> 6;
    const int wr = w >> 1, wc = w & 1;     // wave -> 64x64 quadrant
    const int lr = l & 15, lg = l >> 4;

    f32x4 acc[4][4] = {};
    #pragma unroll
    for (int ks = 0; ks < 4; ++ks) {
        s8v a_f[4], b_f[4];
        #pragma unroll
        for (int mi = 0; mi < 4; ++mi) {
            int row = wr * 64 + mi * 16 + lr;
            int byte = (row * 256 + ks * 64 + lg * 16) ^ ((row & 15) << 4);
            a_f[mi] = *reinterpret_cast<const s8v*>(smc + byte);
        }
        #pragma unroll
        for (int ni = 0; ni < 4; ++ni) {
            int n = wc * 64 + ni * 16 + lr;
            int byte = (n * 256 + ks * 64 + lg * 16) ^ ((n & 15) << 4);
            b_f[ni] = *reinterpret_cast<const s8v*>(smc + 32768 + byte);
        }
        #pragma unroll
        for (int mi = 0; mi < 4; ++mi)
            #pragma unroll
            for (int ni = 0; ni < 4; ++ni)
                acc[mi][ni] = __builtin_amdgcn_mfma_f32_16x16x32_bf16(
                    a_f[mi], b_f[ni], acc[mi][ni], 0, 0, 0);
    }

    float bl[4];
    #pragma unroll
    for (int ni = 0; ni < 4; ++ni) bl[ni] = bg[wc * 64 + ni * 16 + lr];

    #pragma unroll
    for (int mi = 0; mi < 4; ++mi) {
        int rbase = m0 + wr * 64 + mi * 16 + lg * 4;
        #pragma unroll
        for (int ni = 0; ni < 4; ++ni) {
            int col = wc * 64 + ni * 16 + lr;
            #pragma unroll
            for (int q = 0; q < 4; ++q) {
                float v = acc[mi][ni][q] + bl[ni];
                if (DOELU) v = eluf(v);
                C[(size_t)(rbase + q) * 128 + col] = v;
            }
        }
    }
}

// ---------------------------------------------------------------------------
// fp32 GEMM (encoder layer 1 only, K=16): unchanged r2 structure.
// ---------------------------------------------------------------------------
template<int KD, int TM, int DOELU>
__global__ __launch_bounds__(256) void gemm2(const float* __restrict__ A, int lda,
                                             const float* __restrict__ B, int ldb,
                                             const float* __restrict__ bias,
                                             float* __restrict__ C0)
{
    extern __shared__ float sm[];
    float* As = sm;
    float* Bs = sm + TM * (KD + 1);
    const int tid = threadIdx.x;
    const int m0 = blockIdx.x * TM;
    float* C = C0;
    const float* bg = bias;

    constexpr int NF4 = KD / 4;
    for (int e = tid; e < TM * NF4; e += 256) {
        int q = e % NF4, m = e / NF4;
        float4 v = *reinterpret_cast<const float4*>(&A[(size_t)(m0 + m) * lda + 4 * q]);
        float* dst = &As[m * (KD + 1) + 4 * q];
        dst[0] = v.x; dst[1] = v.y; dst[2] = v.z; dst[3] = v.w;
    }
    for (int e = tid; e < KD * 32; e += 256) {
        int q = e & 31, k = e >> 5;
        float4 v = *reinterpret_cast<const float4*>(&B[(size_t)k * ldb + 4 * q]);
        float* dst = &Bs[k * 129 + 4 * q];
        dst[0] = v.x; dst[1] = v.y; dst[2] = v.z; dst[3] = v.w;
    }
    __syncthreads();

    const int tml = tid & 15;
    const int tnh = tid >> 4;
    constexpr int NR = TM / 16;
    float acc[NR][8] = {};
    #pragma unroll 4
    for (int k = 0; k < KD; ++k) {
        float av[NR], bv[8];
        #pragma unroll
        for (int s = 0; s < NR; ++s) av[s] = As[(tml + 16 * s) * (KD + 1) + k];
        #pragma unroll
        for (int u = 0; u < 8; ++u) bv[u] = Bs[k * 129 + tnh + 16 * u];
        #pragma unroll
        for (int s = 0; s < NR; ++s)
            #pragma unroll
            for (int u = 0; u < 8; ++u) acc[s][u] += av[s] * bv[u];
    }
    __syncthreads();
    float* Ce = sm;
    #pragma unroll
    for (int s = 0; s < NR; ++s)
        #pragma unroll
        for (int u = 0; u < 8; ++u)
            Ce[(tml + 16 * s) * 132 + tnh + 16 * u] = acc[s][u];
    __syncthreads();
    for (int e = tid; e < TM * 32; e += 256) {
        int q = e & 31, m = e >> 5;
        float4 v = *reinterpret_cast<const float4*>(&Ce[m * 132 + 4 * q]);
        float4 b4 = *reinterpret_cast<const float4*>(&bg[4 * q]);
        v.x += b4.x; v.y += b4.y; v.z += b4.z; v.w += b4.w;
        if (DOELU) { v.x = eluf(v.x); v.y = eluf(v.y); v.z = eluf(v.z); v.w = eluf(v.w); }
        *reinterpret_cast<float4*>(&C[(size_t)(m0 + m) * 128 + 4 * q]) = v;
    }
}

// ---------------------------------------------------------------------------
// edge v3: 512 threads (2 waves/SIMD). Phases:
//  stage X (all) | Sq b128 (tid<128) | d2 4x8 (tid<256) || c->f16x2 (tid>=256)
//  | radix-select KNN + set-max combine (8 waves x 8 rows).
// LDS: Xs[128][132] | D[64][132] | Sq[128] | Cc[128][64] u32  = 134.7 KB
// ---------------------------------------------------------------------------
__global__ __launch_bounds__(512) void edge_kernel(const float* __restrict__ hin,
                                                   const float* __restrict__ cc,
                                                   float* __restrict__ hio)
{
    extern __shared__ float sm[];
    float* Xs = sm;                                   // [128][132]
    float* D  = sm + 128 * 132;                       // [64][132]
    float* Sq = sm + 128 * 132 + 64 * 132;            // [128]
    unsigned int* Cc = (unsigned int*)(sm + 128 * 132 + 64 * 132 + 128); // [128][64]

    const int g = blockIdx.x >> 1, half = blockIdx.x & 1;
    const int r0 = half * 64;
    const int tid = threadIdx.x;
    const float* hg = hin + (size_t)g * NPTS * FDIM;
    const float* cg = cc  + (size_t)g * NPTS * FDIM;
    float* og = hio + (size_t)g * NPTS * FDIM;

    // stage X
    for (int e = tid; e < 4096; e += 512) {
        int m = e >> 5, q = e & 31;
        float4 v = *reinterpret_cast<const float4*>(&hg[m * 128 + 4 * q]);
        float* dst = &Xs[m * 132 + 4 * q];
        dst[0] = v.x; dst[1] = v.y; dst[2] = v.z; dst[3] = v.w;
    }
    __syncthreads();

    if (tid < 128) {
        float s = 0.f;
        #pragma unroll 8
        for (int c = 0; c < 32; ++c) {
            float4 v = *reinterpret_cast<const float4*>(&Xs[tid * 132 + 4 * c]);
            s += v.x * v.x + v.y * v.y + v.z * v.z + v.w * v.w;
        }
        Sq[tid] = s;
    }
    __syncthreads();

    if (tid < 256) {   // d2: rows r0+tml+16s (s<4), cols tch+16u (u<8)
        const int tml = tid & 15, tch = tid >> 4;
        float acc[4][8] = {};
        #pragma unroll 2
        for (int k = 0; k < 128; ++k) {
            float av[4], bv[8];
            #pragma unroll
            for (int s = 0; s < 4; ++s) av[s] = Xs[(r0 + tml + 16 * s) * 132 + k];
            #pragma unroll
            for (int u = 0; u < 8; ++u) bv[u] = Xs[(tch + 16 * u) * 132 + k];
            #pragma unroll
            for (int s = 0; s < 4; ++s)
                #pragma unroll
                for (int u = 0; u < 8; ++u) acc[s][u] += av[s] * bv[u];
        }
        #pragma unroll
        for (int s = 0; s < 4; ++s) {
            float sqa = Sq[r0 + tml + 16 * s];
            #pragma unroll
            for (int u = 0; u < 8; ++u)
                D[(tml + 16 * s) * 132 + tch + 16 * u] =
                    sqa + Sq[tch + 16 * u] - 2.f * acc[s][u];
        }
    } else {           // stage c as packed f16x2
        for (int e = tid - 256; e < 4096; e += 256) {
            int q = e & 31, j = e >> 5;
            float4 v = *reinterpret_cast<const float4*>(&cg[j * 128 + 4 * q]);
            unsigned int p0 = ((unsigned int)__half_as_ushort(__float2half(v.y)) << 16)
                            |  (unsigned int)__half_as_ushort(__float2half(v.x));
            unsigned int p1 = ((unsigned int)__half_as_ushort(__float2half(v.w)) << 16)
                            |  (unsigned int)__half_as_ushort(__float2half(v.z));
            Cc[j * 64 + 2 * q]     = p0;
            Cc[j * 64 + 2 * q + 1] = p1;
        }
    }
    __syncthreads();

    // 8 waves x 8 rows: radix-select top-24 + combine. lane l: cols {2l,2l+1}.
    const int w = tid >> 6, l = tid & 63;
    const int lrEnd = w * 8 + 8;
    float2 dv = *reinterpret_cast<const float2*>(&D[(w * 8) * 132 + 2 * l]);
    for (int lr = w * 8; lr < lrEnd; ++lr) {
        float2 cur = dv;
        if (lr + 1 < lrEnd)
            dv = *reinterpret_cast<const float2*>(&D[(lr + 1) * 132 + 2 * l]);

        unsigned int ub0 = __float_as_uint(cur.x);
        unsigned int ub1 = __float_as_uint(cur.y);
        unsigned int u0 = (ub0 & 0x80000000u) ? ~ub0 : (ub0 | 0x80000000u);
        unsigned int u1 = (ub1 & 0x80000000u) ? ~ub1 : (ub1 | 0x80000000u);

        bool c0 = true, c1 = true, in0 = false, in1 = false;
        int need = KNNK;
        for (int b = 31; b >= 0; --b) {
            bool z0 = c0 && !((u0 >> b) & 1u);
            bool z1 = c1 && !((u1 >> b) & 1u);
            int cnt = __popcll(__ballot(z0)) + __popcll(__ballot(z1));
            if (cnt > need) { c0 = z0; c1 = z1; }
            else if (cnt == need) { in0 |= z0; in1 |= z1; need = 0; break; }
            else { in0 |= z0; in1 |= z1; need -= cnt;
                   c0 = c0 && !z0; c1 = c1 && !z1; }
        }
        if (need > 0) {
            unsigned long long m0 = __ballot(c0), m1 = __ballot(c1);
            unsigned long long below = (1ull << l) - 1ull;
            int rk0 = __popcll(m0 & below) + __popcll(m1 & below);
            int rk1 = rk0 + (int)((m0 >> l) & 1ull);
            in0 = in0 || (c0 && rk0 < need);
            in1 = in1 || (c1 && rk1 < need);
        }
        unsigned long long s0 = __ballot(in0), s1 = __ballot(in1);

        float2 av = *reinterpret_cast<const float2*>(&og[(r0 + lr) * 128 + 2 * l]);

        float mc0 = -3.0e38f, mc1 = -3.0e38f;
        while (s0) {
            int p = __ffsll((unsigned long long)s0) - 1; s0 &= s0 - 1ull;
            unsigned int cw = Cc[(2 * p) * 64 + l];
            mc0 = fmaxf(mc0, __half2float(__ushort_as_half((unsigned short)(cw & 0xffffu))));
            mc1 = fmaxf(mc1, __half2float(__ushort_as_half((unsigned short)(cw >> 16))));
        }
        while (s1) {
            int p = __ffsll((unsigned long long)s1) - 1; s1 &= s1 - 1ull;
            unsigned int cw = Cc[(2 * p + 1) * 64 + l];
            mc0 = fmaxf(mc0, __half2float(__ushort_as_half((unsigned short)(cw & 0xffffu))));
            mc1 = fmaxf(mc1, __half2float(__ushort_as_half((unsigned short)(cw >> 16))));
        }
        float2 o;
        o.x = eluf(av.x + mc0);
        o.y = eluf(av.y + mc1);
        *reinterpret_cast<float2*>(&og[(r0 + lr) * 128 + 2 * l]) = o;
    }
}

// ---------------------------------------------------------------------------
// head: per-graph sum-pool (4-way split, 512 thr) + 128->64->32->32->6 MLP
// ---------------------------------------------------------------------------
__global__ __launch_bounds__(512) void head_kernel(const float* __restrict__ h,
        const float* __restrict__ w1, const float* __restrict__ b1,
        const float* __restrict__ w2, const float* __restrict__ b2,
        const float* __restrict__ w3, const float* __restrict__ b3,
        const float* __restrict__ w4, const float* __restrict__ b4,
        float* __restrict__ out)
{
    __shared__ float ps[4][128];
    __shared__ float pooled[128], s1[64], s2[32], s3[32];
    const int g = blockIdx.x, t = threadIdx.x;
    const float* hg = h + (size_t)g * NPTS * FDIM;
    const int f = t & 127, hp = t >> 7;
    float s = 0.0f;
    for (int p = 0; p < 32; ++p) s += hg[(hp * 32 + p) * 128 + f];
    ps[hp][f] = s;
    __syncthreads();
    if (t < 128) pooled[t] = ps[0][t] + ps[1][t] + ps[2][t] + ps[3][t];
    __syncthreads();
    if (t < 64) {
        float a = b1[t];
        #pragma unroll 8
        for (int k = 0; k < 128; ++k) a += pooled[k] * w1[k * 64 + t];
        s1[t] = eluf(a);
    }
    __syncthreads();
    if (t < 32) {
        float a = b2[t];
        #pragma unroll 8
        for (int k = 0; k < 64; ++k) a += s1[k] * w2[k * 32 + t];
        s2[t] = eluf(a);
    }
    __syncthreads();
    if (t < 32) {
        float a = b3[t];
        #pragma unroll 8
        for (int k = 0; k < 32; ++k) a += s2[k] * w3[k * 32 + t];
        s3[t] = eluf(a);
    }
    __syncthreads();
    if (t < 6) {
        float a = b4[t];
        #pragma unroll 8
        for (int k = 0; k < 32; ++k) a += s3[k] * w4[k * 6 + t];
        out[g * 6 + t] = a;
    }
}

__global__ void batch_kernel(const int* __restrict__ bpf, float* __restrict__ out)
{
    int i = blockIdx.x * 256 + threadIdx.x;
    if (i < NTOT) out[768 + i] = (float)bpf[i];
}

// ---------------------------------------------------------------------------
extern "C" void kernel_launch(void* const* d_in, const int* in_sizes, int n_in,
                              void* d_out, int out_size, void* d_ws, size_t ws_size,
                              hipStream_t stream)
{
    const float* x_pf   = (const float*)d_in[0];
    const float* enc_w1 = (const float*)d_in[1];
    const float* enc_b1 = (const float*)d_in[2];
    const float* enc_w2 = (const float*)d_in[3];
    const float* enc_b2 = (const float*)d_in[4];
    const float* c1w = (const float*)d_in[5];
    const float* c1b = (const float*)d_in[6];
    const float* c2w = (const float*)d_in[7];
    const float* c2b = (const float*)d_in[8];
    const float* c3w = (const float*)d_in[9];
    const float* c3b = (const float*)d_in[10];
    const float* o_w1 = (const float*)d_in[11];
    const float* o_b1 = (const float*)d_in[12];
    const float* o_w2 = (const float*)d_in[13];
    const float* o_b2 = (const float*)d_in[14];
    const float* o_w3 = (const float*)d_in[15];
    const float* o_b3 = (const float*)d_in[16];
    const float* o_w4 = (const float*)d_in[17];
    const float* o_b4 = (const float*)d_in[18];
    const int*   bpf  = (const int*)d_in[19];
    float* out = (float*)d_out;

    float* ws   = (float*)d_ws;
    float* h_a  = ws;                              // 16384*128 f32
    float* h_b  = h_a + (size_t)NTOT * FDIM;       // 16384*128 f32
    float* ac_c = h_b + (size_t)NTOT * FDIM;       // 16384*128 f32 (enc1 out / c)
    unsigned short* wcatT = (unsigned short*)(ac_c + (size_t)NTOT * FDIM); // 3*256*128 bf16
    unsigned short* enc2T = wcatT + 3 * 32768;     // 128*128 bf16
    float* biasF = (float*)(enc2T + 16384);        // 3*256 f32

    prep_kernel<<<451, 256, 0, stream>>>(c1w, c2w, c3w, enc_w2,
                                         c1b, c2b, c3b, wcatT, enc2T, biasF);

    // encoder
    gemm2<16, 64, 1><<<dim3(NTOT / 64, 1), 256, 8448 * 4, stream>>>(
        x_pf, 16, enc_w1, 128, enc_b1, ac_c);
    gemmT<1><<<dim3(NTOT / 128, 1), 256, 65536, stream>>>(
        ac_c, enc2T, enc_b2, h_a, nullptr);

    const size_t lds_edge = (size_t)(128 * 132 + 64 * 132 + 128 + 128 * 64) * 4;

    float* hc = h_a;
    float* hn = h_b;
    for (int l = 0; l < 3; ++l) {
        gemmT<0><<<dim3(NTOT / 128, 2), 256, 65536, stream>>>(
            hc, wcatT + (size_t)l * 32768, biasF + l * 256, hn, ac_c);
        edge_kernel<<<2 * G_NUM, 512, lds_edge, stream>>>(hc, ac_c, hn);
        float* t = hc; hc = hn; hn = t;
    }

    head_kernel<<<G_NUM, 512, 0, stream>>>(hc, o_w1, o_b1, o_w2, o_b2, o_w3, o_b3,
                                           o_w4, o_b4, out);
    batch_kernel<<<64, 256, 0, stream>>>(bpf, out);
}

// Round 4
// 298.837 us; speedup vs baseline: 1.6660x; 1.1338x over previous
//
#include <hip/hip_runtime.h>
#include <hip/hip_fp16.h>
#include <hip/hip_bf16.h>
#include <cmath>

#define G_NUM 128
#define NPTS  128
#define FDIM  128
#define KNNK  24
#define NTOT  (G_NUM*NPTS)   // 16384

typedef short s8v __attribute__((ext_vector_type(8)));   // 8 bf16 (4 VGPRs)
typedef float f32x4 __attribute__((ext_vector_type(4))); // MFMA accumulator

__device__ __forceinline__ float eluf(float x){ return x > 0.0f ? x : expm1f(x); }

__device__ __forceinline__ unsigned short f2bf(float f) {
    unsigned int u = __float_as_uint(f);
    unsigned int r = (u + 0x7fffu + ((u >> 16) & 1u)) >> 16;   // RNE
    return (unsigned short)r;
}
__device__ __forceinline__ float bf2f(unsigned short b) {
    return __uint_as_float(((unsigned int)b) << 16);
}

// ---------------------------------------------------------------------------
// prep: wcatT[l][n][k] bf16 (n<128: Wtop-Wbot col, else Wbot col), enc2T[n][k]
// bf16, bias[l][256] f32 (c-half zero). Also writes batch_pf -> out[768..].
// ---------------------------------------------------------------------------
__global__ void prep_kernel(const float* __restrict__ w1, const float* __restrict__ w2,
                            const float* __restrict__ w3, const float* __restrict__ ew2,
                            const float* __restrict__ b1, const float* __restrict__ b2,
                            const float* __restrict__ b3,
                            unsigned short* __restrict__ wcatT,
                            unsigned short* __restrict__ enc2T,
                            float* __restrict__ bias,
                            const int* __restrict__ bpf,
                            float* __restrict__ out)
{
    int e = blockIdx.x * 256 + threadIdx.x;
    if (e < 16384) out[768 + e] = (float)bpf[e];
    if (e < 98304) {                       // 3 * 128k * 256n
        int l = e >> 15;
        int r = e & 32767;
        int k = r >> 8;                    // 0..127
        int n = r & 255;                   // 0..255
        const float* w = (l == 0) ? w1 : ((l == 1) ? w2 : w3);
        float v = (n < 128) ? (w[k * 128 + n] - w[(128 + k) * 128 + n])
                            : w[(128 + k) * 128 + (n - 128)];
        wcatT[l * 32768 + n * 128 + k] = f2bf(v);
    } else if (e < 114688) {               // enc2T: 128k * 128n
        int i = e - 98304;
        int k = i >> 7, n = i & 127;
        enc2T[n * 128 + k] = f2bf(ew2[k * 128 + n]);
    } else if (e < 115456) {
        int j = e - 114688;
        int l = j >> 8, c = j & 255;
        const float* b = (l == 0) ? b1 : ((l == 1) ? b2 : b3);
        bias[l * 256 + c] = (c < 128) ? b[c] : 0.0f;
    }
}

// ---------------------------------------------------------------------------
// MFMA GEMM (unchanged r3): C = act(A[M x 128] @ B + bias). BM=128, BN=128.
// ---------------------------------------------------------------------------
template<int DOELU>
__global__ __launch_bounds__(256) void gemmT(const float* __restrict__ A,
                                             const unsigned short* __restrict__ Bt,
                                             const float* __restrict__ bias,
                                             float* __restrict__ C0,
                                             float* __restrict__ C1)
{
    extern __shared__ char smc[];
    const int tid = threadIdx.x;
    const int m0 = blockIdx.x * 128;
    const unsigned short* Btg = Bt + (size_t)blockIdx.y * 16384;
    const float* bg = bias + blockIdx.y * 128;
    float* C = blockIdx.y ? C1 : C0;

    for (int e = tid; e < 4096; e += 256) {
        int m = e >> 5, q = e & 31;
        float4 v = *reinterpret_cast<const float4*>(&A[(size_t)(m0 + m) * 128 + 4 * q]);
        ushort4 p;
        p.x = f2bf(v.x); p.y = f2bf(v.y); p.z = f2bf(v.z); p.w = f2bf(v.w);
        int byte = (m * 256 + q * 8) ^ ((m & 15) << 4);
        *reinterpret_cast<ushort4*>(smc + byte) = p;
    }
    for (int e = tid; e < 2048; e += 256) {
        int n = e >> 4, q = e & 15;
        uint4 v = *reinterpret_cast<const uint4*>(Btg + n * 128 + q * 8);
        int byte = (n * 256 + q * 16) ^ ((n & 15) << 4);
        *reinterpret_cast<uint4*>(smc + 32768 + byte) = v;
    }
    __syncthreads();

    const int l = tid & 63, w = tid >> 6;
    const int wr = w >> 1, wc = w & 1;
    const int lr = l & 15, lg = l >> 4;

    f32x4 acc[4][4] = {};
    #pragma unroll
    for (int ks = 0; ks < 4; ++ks) {
        s8v a_f[4], b_f[4];
        #pragma unroll
        for (int mi = 0; mi < 4; ++mi) {
            int row = wr * 64 + mi * 16 + lr;
            int byte = (row * 256 + ks * 64 + lg * 16) ^ ((row & 15) << 4);
            a_f[mi] = *reinterpret_cast<const s8v*>(smc + byte);
        }
        #pragma unroll
        for (int ni = 0; ni < 4; ++ni) {
            int n = wc * 64 + ni * 16 + lr;
            int byte = (n * 256 + ks * 64 + lg * 16) ^ ((n & 15) << 4);
            b_f[ni] = *reinterpret_cast<const s8v*>(smc + 32768 + byte);
        }
        #pragma unroll
        for (int mi = 0; mi < 4; ++mi)
            #pragma unroll
            for (int ni = 0; ni < 4; ++ni)
                acc[mi][ni] = __builtin_amdgcn_mfma_f32_16x16x32_bf16(
                    a_f[mi], b_f[ni], acc[mi][ni], 0, 0, 0);
    }

    float bl[4];
    #pragma unroll
    for (int ni = 0; ni < 4; ++ni) bl[ni] = bg[wc * 64 + ni * 16 + lr];

    #pragma unroll
    for (int mi = 0; mi < 4; ++mi) {
        int rbase = m0 + wr * 64 + mi * 16 + lg * 4;
        #pragma unroll
        for (int ni = 0; ni < 4; ++ni) {
            int col = wc * 64 + ni * 16 + lr;
            #pragma unroll
            for (int q = 0; q < 4; ++q) {
                float v = acc[mi][ni][q] + bl[ni];
                if (DOELU) v = eluf(v);
                C[(size_t)(rbase + q) * 128 + col] = v;
            }
        }
    }
}

// ---------------------------------------------------------------------------
// fp32 GEMM (encoder layer 1 only, K=16): unchanged.
// ---------------------------------------------------------------------------
template<int KD, int TM, int DOELU>
__global__ __launch_bounds__(256) void gemm2(const float* __restrict__ A, int lda,
                                             const float* __restrict__ B, int ldb,
                                             const float* __restrict__ bias,
                                             float* __restrict__ C0)
{
    extern __shared__ float sm[];
    float* As = sm;
    float* Bs = sm + TM * (KD + 1);
    const int tid = threadIdx.x;
    const int m0 = blockIdx.x * TM;
    float* C = C0;
    const float* bg = bias;

    constexpr int NF4 = KD / 4;
    for (int e = tid; e < TM * NF4; e += 256) {
        int q = e % NF4, m = e / NF4;
        float4 v = *reinterpret_cast<const float4*>(&A[(size_t)(m0 + m) * lda + 4 * q]);
        float* dst = &As[m * (KD + 1) + 4 * q];
        dst[0] = v.x; dst[1] = v.y; dst[2] = v.z; dst[3] = v.w;
    }
    for (int e = tid; e < KD * 32; e += 256) {
        int q = e & 31, k = e >> 5;
        float4 v = *reinterpret_cast<const float4*>(&B[(size_t)k * ldb + 4 * q]);
        float* dst = &Bs[k * 129 + 4 * q];
        dst[0] = v.x; dst[1] = v.y; dst[2] = v.z; dst[3] = v.w;
    }
    __syncthreads();

    const int tml = tid & 15;
    const int tnh = tid >> 4;
    constexpr int NR = TM / 16;
    float acc[NR][8] = {};
    #pragma unroll 4
    for (int k = 0; k < KD; ++k) {
        float av[NR], bv[8];
        #pragma unroll
        for (int s = 0; s < NR; ++s) av[s] = As[(tml + 16 * s) * (KD + 1) + k];
        #pragma unroll
        for (int u = 0; u < 8; ++u) bv[u] = Bs[k * 129 + tnh + 16 * u];
        #pragma unroll
        for (int s = 0; s < NR; ++s)
            #pragma unroll
            for (int u = 0; u < 8; ++u) acc[s][u] += av[s] * bv[u];
    }
    __syncthreads();
    float* Ce = sm;
    #pragma unroll
    for (int s = 0; s < NR; ++s)
        #pragma unroll
        for (int u = 0; u < 8; ++u)
            Ce[(tml + 16 * s) * 132 + tnh + 16 * u] = acc[s][u];
    __syncthreads();
    for (int e = tid; e < TM * 32; e += 256) {
        int q = e & 31, m = e >> 5;
        float4 v = *reinterpret_cast<const float4*>(&Ce[m * 132 + 4 * q]);
        float4 b4 = *reinterpret_cast<const float4*>(&bg[4 * q]);
        v.x += b4.x; v.y += b4.y; v.z += b4.z; v.w += b4.w;
        if (DOELU) { v.x = eluf(v.x); v.y = eluf(v.y); v.z = eluf(v.z); v.w = eluf(v.w); }
        *reinterpret_cast<float4*>(&C[(size_t)(m0 + m) * 128 + 4 * q]) = v;
    }
}

// ---------------------------------------------------------------------------
// edge v4: 512 thr, 2 blocks/graph (rows r0..r0+63).
// Phase1: split-stage X -> Xhi/Xlo bf16 (swizzled) + Sq via shfl reduce.
// Phase2: waves 0-3: d2 = Sq_i+Sq_j-2*(XhiXhi'+XhiXlo'+XloXhi') via MFMA;
//         waves 4-7: stage c as f16x2 into Cc.
// Phase3: 8 waves x 8 rows: radix-select top-24 -> compact idx list ->
//         static 24-trip combine (2 rows/wave, ds_read_b64, float4 a/o).
// LDS: Xhi 32K | Xlo 32K | D[64][132] 33K | Sq 0.5K | idx[64][24] 6K | Cc 32K
//      = 138752 B  (1 block/CU, 8 waves)
// ---------------------------------------------------------------------------
#define XHI_OFF 0
#define XLO_OFF 32768
#define D_OFF   65536
#define SQ_OFF  99328
#define IDX_OFF 99840
#define CC_OFF  105984
#define EDGE_LDS 138752

__global__ __launch_bounds__(512) void edge_kernel(const float* __restrict__ hin,
                                                   const float* __restrict__ cc,
                                                   float* __restrict__ hio)
{
    extern __shared__ char smc[];
    float* D  = (float*)(smc + D_OFF);          // [64][132]
    float* Sq = (float*)(smc + SQ_OFF);         // [128]
    unsigned int* idxL = (unsigned int*)(smc + IDX_OFF); // [64][24]
    unsigned int* Cc   = (unsigned int*)(smc + CC_OFF);  // [128][64]

    const int g = blockIdx.x >> 1, half = blockIdx.x & 1;
    const int r0 = half * 64;
    const int tid = threadIdx.x;
    const float* hg = hin + (size_t)g * NPTS * FDIM;
    const float* cg = cc  + (size_t)g * NPTS * FDIM;
    float* og = hio + (size_t)g * NPTS * FDIM;

    // ---- phase 1: split-stage X + Sq ----
    {
        const int m = tid >> 2;            // row 0..127
        const int k0 = (tid & 3) * 32;     // quarter
        float sq = 0.f;
        #pragma unroll
        for (int i = 0; i < 8; ++i) {
            float4 v = *reinterpret_cast<const float4*>(&hg[m * 128 + k0 + 4 * i]);
            ushort4 hi, lo;
            hi.x = f2bf(v.x); lo.x = f2bf(v.x - bf2f(hi.x));
            hi.y = f2bf(v.y); lo.y = f2bf(v.y - bf2f(hi.y));
            hi.z = f2bf(v.z); lo.z = f2bf(v.z - bf2f(hi.z));
            hi.w = f2bf(v.w); lo.w = f2bf(v.w - bf2f(hi.w));
            sq += v.x * v.x + v.y * v.y + v.z * v.z + v.w * v.w;
            int byte = (m * 256 + (k0 + 4 * i) * 2) ^ ((m & 15) << 4);
            *reinterpret_cast<ushort4*>(smc + XHI_OFF + byte) = hi;
            *reinterpret_cast<ushort4*>(smc + XLO_OFF + byte) = lo;
        }
        sq += __shfl_xor(sq, 1);
        sq += __shfl_xor(sq, 2);
        if ((tid & 3) == 0) Sq[m] = sq;
    }
    __syncthreads();

    // ---- phase 2: d2 MFMA (waves 0-3) || c staging (waves 4-7) ----
    if (tid < 256) {
        const int w = tid >> 6;            // 0..3 -> rows w*16..w*16+15 (block-local)
        const int l = tid & 63;
        const int lr = l & 15, lg = l >> 4;
        const int arow = r0 + w * 16 + lr;
        const int aswz = (arow & 15) << 4;

        f32x4 acc[8] = {};
        #pragma unroll
        for (int ks = 0; ks < 4; ++ks) {
            int abyte = (arow * 256 + ks * 64 + lg * 16) ^ aswz;
            s8v ahi = *reinterpret_cast<const s8v*>(smc + XHI_OFF + abyte);
            s8v alo = *reinterpret_cast<const s8v*>(smc + XLO_OFF + abyte);
            #pragma unroll
            for (int ni = 0; ni < 8; ++ni) {
                int brow = ni * 16 + lr;
                int bbyte = (brow * 256 + ks * 64 + lg * 16) ^ ((brow & 15) << 4);
                s8v bhi = *reinterpret_cast<const s8v*>(smc + XHI_OFF + bbyte);
                s8v blo = *reinterpret_cast<const s8v*>(smc + XLO_OFF + bbyte);
                acc[ni] = __builtin_amdgcn_mfma_f32_16x16x32_bf16(alo, bhi, acc[ni], 0, 0, 0);
                acc[ni] = __builtin_amdgcn_mfma_f32_16x16x32_bf16(ahi, blo, acc[ni], 0, 0, 0);
                acc[ni] = __builtin_amdgcn_mfma_f32_16x16x32_bf16(ahi, bhi, acc[ni], 0, 0, 0);
            }
        }
        float sqa[4];
        #pragma unroll
        for (int q = 0; q < 4; ++q) sqa[q] = Sq[r0 + w * 16 + lg * 4 + q];
        #pragma unroll
        for (int ni = 0; ni < 8; ++ni) {
            float sqc = Sq[ni * 16 + lr];
            #pragma unroll
            for (int q = 0; q < 4; ++q)
                D[(w * 16 + lg * 4 + q) * 132 + ni * 16 + lr] =
                    sqa[q] + sqc - 2.f * acc[ni][q];
        }
    } else {
        for (int e = tid - 256; e < 4096; e += 256) {
            int q = e & 31, j = e >> 5;
            float4 v = *reinterpret_cast<const float4*>(&cg[j * 128 + 4 * q]);
            unsigned int p0 = ((unsigned int)__half_as_ushort(__float2half(v.y)) << 16)
                            |  (unsigned int)__half_as_ushort(__float2half(v.x));
            unsigned int p1 = ((unsigned int)__half_as_ushort(__float2half(v.w)) << 16)
                            |  (unsigned int)__half_as_ushort(__float2half(v.z));
            Cc[j * 64 + 2 * q]     = p0;
            Cc[j * 64 + 2 * q + 1] = p1;
        }
    }
    __syncthreads();

    // ---- phase 3: KNN radix-select + compact + combine ----
    const int w8 = tid >> 6, l = tid & 63;

    for (int lr2 = w8 * 8; lr2 < w8 * 8 + 8; ++lr2) {
        float2 cur = *reinterpret_cast<const float2*>(&D[lr2 * 132 + 2 * l]);
        unsigned int ub0 = __float_as_uint(cur.x);
        unsigned int ub1 = __float_as_uint(cur.y);
        unsigned int u0 = (ub0 & 0x80000000u) ? ~ub0 : (ub0 | 0x80000000u);
        unsigned int u1 = (ub1 & 0x80000000u) ? ~ub1 : (ub1 | 0x80000000u);

        bool c0 = true, c1 = true, in0 = false, in1 = false;
        int need = KNNK;
        for (int b = 31; b >= 0; --b) {
            bool z0 = c0 && !((u0 >> b) & 1u);
            bool z1 = c1 && !((u1 >> b) & 1u);
            int cnt = __popcll(__ballot(z0)) + __popcll(__ballot(z1));
            if (cnt > need) { c0 = z0; c1 = z1; }
            else if (cnt == need) { in0 |= z0; in1 |= z1; need = 0; break; }
            else { in0 |= z0; in1 |= z1; need -= cnt;
                   c0 = c0 && !z0; c1 = c1 && !z1; }
        }
        if (need > 0) {
            unsigned long long m0 = __ballot(c0), m1 = __ballot(c1);
            unsigned long long below = (1ull << l) - 1ull;
            int rk0 = __popcll(m0 & below) + __popcll(m1 & below);
            int rk1 = rk0 + (int)((m0 >> l) & 1ull);
            in0 = in0 || (c0 && rk0 < need);
            in1 = in1 || (c1 && rk1 < need);
        }
        unsigned long long f0 = __ballot(in0), f1 = __ballot(in1);
        int cnt0 = __popcll(f0);
        unsigned long long below = (1ull << l) - 1ull;
        if (in0) idxL[lr2 * KNNK + __popcll(f0 & below)] = 2 * l;
        if (in1) idxL[lr2 * KNNK + cnt0 + __popcll(f1 & below)] = 2 * l + 1;
    }

    // combine: 2 rows per pass, lane covers 4 features (uint2 of f16x2).
    {
        const int hh = l >> 5, j = l & 31;
        #pragma unroll
        for (int u = 0; u < 4; ++u) {
            const int r = w8 * 8 + 2 * u + hh;
            const unsigned int* il = &idxL[r * KNNK];
            float mc0 = -3.0e38f, mc1 = -3.0e38f, mc2 = -3.0e38f, mc3 = -3.0e38f;
            #pragma unroll
            for (int t = 0; t < KNNK; t += 4) {
                unsigned int p0 = il[t], p1 = il[t + 1], p2 = il[t + 2], p3 = il[t + 3];
                uint2 a = *reinterpret_cast<const uint2*>(&Cc[p0 * 64 + 2 * j]);
                uint2 b = *reinterpret_cast<const uint2*>(&Cc[p1 * 64 + 2 * j]);
                uint2 c = *reinterpret_cast<const uint2*>(&Cc[p2 * 64 + 2 * j]);
                uint2 d = *reinterpret_cast<const uint2*>(&Cc[p3 * 64 + 2 * j]);
                mc0 = fmaxf(fmaxf(mc0,
                        __half2float(__ushort_as_half((unsigned short)(a.x & 0xffffu)))),
                        fmaxf(__half2float(__ushort_as_half((unsigned short)(b.x & 0xffffu))),
                              fmaxf(__half2float(__ushort_as_half((unsigned short)(c.x & 0xffffu))),
                                    __half2float(__ushort_as_half((unsigned short)(d.x & 0xffffu))))));
                mc1 = fmaxf(fmaxf(mc1,
                        __half2float(__ushort_as_half((unsigned short)(a.x >> 16)))),
                        fmaxf(__half2float(__ushort_as_half((unsigned short)(b.x >> 16))),
                              fmaxf(__half2float(__ushort_as_half((unsigned short)(c.x >> 16))),
                                    __half2float(__ushort_as_half((unsigned short)(d.x >> 16))))));
                mc2 = fmaxf(fmaxf(mc2,
                        __half2float(__ushort_as_half((unsigned short)(a.y & 0xffffu)))),
                        fmaxf(__half2float(__ushort_as_half((unsigned short)(b.y & 0xffffu))),
                              fmaxf(__half2float(__ushort_as_half((unsigned short)(c.y & 0xffffu))),
                                    __half2float(__ushort_as_half((unsigned short)(d.y & 0xffffu))))));
                mc3 = fmaxf(fmaxf(mc3,
                        __half2float(__ushort_as_half((unsigned short)(a.y >> 16)))),
                        fmaxf(__half2float(__ushort_as_half((unsigned short)(b.y >> 16))),
                              fmaxf(__half2float(__ushort_as_half((unsigned short)(c.y >> 16))),
                                    __half2float(__ushort_as_half((unsigned short)(d.y >> 16))))));
            }
            float4 av = *reinterpret_cast<const float4*>(&og[(r0 + r) * 128 + 4 * j]);
            float4 o;
            o.x = eluf(av.x + mc0);
            o.y = eluf(av.y + mc1);
            o.z = eluf(av.z + mc2);
            o.w = eluf(av.w + mc3);
            *reinterpret_cast<float4*>(&og[(r0 + r) * 128 + 4 * j]) = o;
        }
    }
}

// ---------------------------------------------------------------------------
// head: per-graph sum-pool (4-way split, 512 thr) + 128->64->32->32->6 MLP
// ---------------------------------------------------------------------------
__global__ __launch_bounds__(512) void head_kernel(const float* __restrict__ h,
        const float* __restrict__ w1, const float* __restrict__ b1,
        const float* __restrict__ w2, const float* __restrict__ b2,
        const float* __restrict__ w3, const float* __restrict__ b3,
        const float* __restrict__ w4, const float* __restrict__ b4,
        float* __restrict__ out)
{
    __shared__ float ps[4][128];
    __shared__ float pooled[128], s1[64], s2[32], s3[32];
    const int g = blockIdx.x, t = threadIdx.x;
    const float* hg = h + (size_t)g * NPTS * FDIM;
    const int f = t & 127, hp = t >> 7;
    float s = 0.0f;
    for (int p = 0; p < 32; ++p) s += hg[(hp * 32 + p) * 128 + f];
    ps[hp][f] = s;
    __syncthreads();
    if (t < 128) pooled[t] = ps[0][t] + ps[1][t] + ps[2][t] + ps[3][t];
    __syncthreads();
    if (t < 64) {
        float a = b1[t];
        #pragma unroll 8
        for (int k = 0; k < 128; ++k) a += pooled[k] * w1[k * 64 + t];
        s1[t] = eluf(a);
    }
    __syncthreads();
    if (t < 32) {
        float a = b2[t];
        #pragma unroll 8
        for (int k = 0; k < 64; ++k) a += s1[k] * w2[k * 32 + t];
        s2[t] = eluf(a);
    }
    __syncthreads();
    if (t < 32) {
        float a = b3[t];
        #pragma unroll 8
        for (int k = 0; k < 32; ++k) a += s2[k] * w3[k * 32 + t];
        s3[t] = eluf(a);
    }
    __syncthreads();
    if (t < 6) {
        float a = b4[t];
        #pragma unroll 8
        for (int k = 0; k < 32; ++k) a += s3[k] * w4[k * 6 + t];
        out[g * 6 + t] = a;
    }
}

// ---------------------------------------------------------------------------
extern "C" void kernel_launch(void* const* d_in, const int* in_sizes, int n_in,
                              void* d_out, int out_size, void* d_ws, size_t ws_size,
                              hipStream_t stream)
{
    const float* x_pf   = (const float*)d_in[0];
    const float* enc_w1 = (const float*)d_in[1];
    const float* enc_b1 = (const float*)d_in[2];
    const float* enc_w2 = (const float*)d_in[3];
    const float* enc_b2 = (const float*)d_in[4];
    const float* c1w = (const float*)d_in[5];
    const float* c1b = (const float*)d_in[6];
    const float* c2w = (const float*)d_in[7];
    const float* c2b = (const float*)d_in[8];
    const float* c3w = (const float*)d_in[9];
    const float* c3b = (const float*)d_in[10];
    const float* o_w1 = (const float*)d_in[11];
    const float* o_b1 = (const float*)d_in[12];
    const float* o_w2 = (const float*)d_in[13];
    const float* o_b2 = (const float*)d_in[14];
    const float* o_w3 = (const float*)d_in[15];
    const float* o_b3 = (const float*)d_in[16];
    const float* o_w4 = (const float*)d_in[17];
    const float* o_b4 = (const float*)d_in[18];
    const int*   bpf  = (const int*)d_in[19];
    float* out = (float*)d_out;

    float* ws   = (float*)d_ws;
    float* h_a  = ws;                              // 16384*128 f32
    float* h_b  = h_a + (size_t)NTOT * FDIM;       // 16384*128 f32
    float* ac_c = h_b + (size_t)NTOT * FDIM;       // 16384*128 f32 (enc1 out / c)
    unsigned short* wcatT = (unsigned short*)(ac_c + (size_t)NTOT * FDIM); // 3*256*128 bf16
    unsigned short* enc2T = wcatT + 3 * 32768;     // 128*128 bf16
    float* biasF = (float*)(enc2T + 16384);        // 3*256 f32

    prep_kernel<<<451, 256, 0, stream>>>(c1w, c2w, c3w, enc_w2,
                                         c1b, c2b, c3b, wcatT, enc2T, biasF,
                                         bpf, out);

    // encoder
    gemm2<16, 64, 1><<<dim3(NTOT / 64, 1), 256, 8448 * 4, stream>>>(
        x_pf, 16, enc_w1, 128, enc_b1, ac_c);
    gemmT<1><<<dim3(NTOT / 128, 1), 256, 65536, stream>>>(
        ac_c, enc2T, enc_b2, h_a, nullptr);

    float* hc = h_a;
    float* hn = h_b;
    for (int l = 0; l < 3; ++l) {
        gemmT<0><<<dim3(NTOT / 128, 2), 256, 65536, stream>>>(
            hc, wcatT + (size_t)l * 32768, biasF + l * 256, hn, ac_c);
        edge_kernel<<<2 * G_NUM, 512, EDGE_LDS, stream>>>(hc, ac_c, hn);
        float* t = hc; hc = hn; hn = t;
    }

    head_kernel<<<G_NUM, 512, 0, stream>>>(hc, o_w1, o_b1, o_w2, o_b2, o_w3, o_b3,
                                           o_w4, o_b4, out);
}

// Round 5
// 292.502 us; speedup vs baseline: 1.7021x; 1.0217x over previous
//
#include <hip/hip_runtime.h>
#include <hip/hip_fp16.h>
#include <hip/hip_bf16.h>
#include <cmath>

#define G_NUM 128
#define NPTS  128
#define FDIM  128
#define KNNK  24
#define NTOT  (G_NUM*NPTS)   // 16384

typedef short s8v __attribute__((ext_vector_type(8)));   // 8 bf16 (4 VGPRs)
typedef float f32x4 __attribute__((ext_vector_type(4))); // MFMA accumulator

__device__ __forceinline__ float eluf(float x){ return x > 0.0f ? x : expm1f(x); }

__device__ __forceinline__ unsigned short f2bf(float f) {
    unsigned int u = __float_as_uint(f);
    unsigned int r = (u + 0x7fffu + ((u >> 16) & 1u)) >> 16;   // RNE
    return (unsigned short)r;
}
__device__ __forceinline__ float bf2f(unsigned short b) {
    return __uint_as_float(((unsigned int)b) << 16);
}

// ---------------------------------------------------------------------------
// prep: wcatT[l][n][k] bf16 (n<128: Wtop-Wbot col, else Wbot col), enc2T[n][k]
// bf16, bias[l][256] f32 (c-half zero). Also writes batch_pf -> out[768..].
// ---------------------------------------------------------------------------
__global__ void prep_kernel(const float* __restrict__ w1, const float* __restrict__ w2,
                            const float* __restrict__ w3, const float* __restrict__ ew2,
                            const float* __restrict__ b1, const float* __restrict__ b2,
                            const float* __restrict__ b3,
                            unsigned short* __restrict__ wcatT,
                            unsigned short* __restrict__ enc2T,
                            float* __restrict__ bias,
                            const int* __restrict__ bpf,
                            float* __restrict__ out)
{
    int e = blockIdx.x * 256 + threadIdx.x;
    if (e < 16384) out[768 + e] = (float)bpf[e];
    if (e < 98304) {                       // 3 * 128k * 256n
        int l = e >> 15;
        int r = e & 32767;
        int k = r >> 8;                    // 0..127
        int n = r & 255;                   // 0..255
        const float* w = (l == 0) ? w1 : ((l == 1) ? w2 : w3);
        float v = (n < 128) ? (w[k * 128 + n] - w[(128 + k) * 128 + n])
                            : w[(128 + k) * 128 + (n - 128)];
        wcatT[l * 32768 + n * 128 + k] = f2bf(v);
    } else if (e < 114688) {               // enc2T: 128k * 128n
        int i = e - 98304;
        int k = i >> 7, n = i & 127;
        enc2T[n * 128 + k] = f2bf(ew2[k * 128 + n]);
    } else if (e < 115456) {
        int j = e - 114688;
        int l = j >> 8, c = j & 255;
        const float* b = (l == 0) ? b1 : ((l == 1) ? b2 : b3);
        bias[l * 256 + c] = (c < 128) ? b[c] : 0.0f;
    }
}

// ---------------------------------------------------------------------------
// MFMA GEMM (encoder layer 2): C = elu(A @ B + bias). Unchanged structure.
// ---------------------------------------------------------------------------
template<int DOELU>
__global__ __launch_bounds__(256) void gemmT(const float* __restrict__ A,
                                             const unsigned short* __restrict__ Bt,
                                             const float* __restrict__ bias,
                                             float* __restrict__ C0)
{
    extern __shared__ char smc[];
    const int tid = threadIdx.x;
    const int m0 = blockIdx.x * 128;
    float* C = C0;

    for (int e = tid; e < 4096; e += 256) {
        int m = e >> 5, q = e & 31;
        float4 v = *reinterpret_cast<const float4*>(&A[(size_t)(m0 + m) * 128 + 4 * q]);
        ushort4 p;
        p.x = f2bf(v.x); p.y = f2bf(v.y); p.z = f2bf(v.z); p.w = f2bf(v.w);
        int byte = (m * 256 + q * 8) ^ ((m & 15) << 4);
        *reinterpret_cast<ushort4*>(smc + byte) = p;
    }
    for (int e = tid; e < 2048; e += 256) {
        int n = e >> 4, q = e & 15;
        uint4 v = *reinterpret_cast<const uint4*>(Bt + n * 128 + q * 8);
        int byte = (n * 256 + q * 16) ^ ((n & 15) << 4);
        *reinterpret_cast<uint4*>(smc + 32768 + byte) = v;
    }
    __syncthreads();

    const int l = tid & 63, w = tid >> 6;
    const int wr = w >> 1, wc = w & 1;
    const int lr = l & 15, lg = l >> 4;

    f32x4 acc[4][4] = {};
    #pragma unroll
    for (int ks = 0; ks < 4; ++ks) {
        s8v a_f[4], b_f[4];
        #pragma unroll
        for (int mi = 0; mi < 4; ++mi) {
            int row = wr * 64 + mi * 16 + lr;
            int byte = (row * 256 + ks * 64 + lg * 16) ^ ((row & 15) << 4);
            a_f[mi] = *reinterpret_cast<const s8v*>(smc + byte);
        }
        #pragma unroll
        for (int ni = 0; ni < 4; ++ni) {
            int n = wc * 64 + ni * 16 + lr;
            int byte = (n * 256 + ks * 64 + lg * 16) ^ ((n & 15) << 4);
            b_f[ni] = *reinterpret_cast<const s8v*>(smc + 32768 + byte);
        }
        #pragma unroll
        for (int mi = 0; mi < 4; ++mi)
            #pragma unroll
            for (int ni = 0; ni < 4; ++ni)
                acc[mi][ni] = __builtin_amdgcn_mfma_f32_16x16x32_bf16(
                    a_f[mi], b_f[ni], acc[mi][ni], 0, 0, 0);
    }

    float bl[4];
    #pragma unroll
    for (int ni = 0; ni < 4; ++ni) bl[ni] = bias[wc * 64 + ni * 16 + lr];

    #pragma unroll
    for (int mi = 0; mi < 4; ++mi) {
        int rbase = m0 + wr * 64 + mi * 16 + lg * 4;
        #pragma unroll
        for (int ni = 0; ni < 4; ++ni) {
            int col = wc * 64 + ni * 16 + lr;
            #pragma unroll
            for (int q = 0; q < 4; ++q) {
                float v = acc[mi][ni][q] + bl[ni];
                if (DOELU) v = eluf(v);
                C[(size_t)(rbase + q) * 128 + col] = v;
            }
        }
    }
}

// ---------------------------------------------------------------------------
// fp32 GEMM (encoder layer 1 only, K=16): unchanged.
// ---------------------------------------------------------------------------
template<int KD, int TM, int DOELU>
__global__ __launch_bounds__(256) void gemm2(const float* __restrict__ A, int lda,
                                             const float* __restrict__ B, int ldb,
                                             const float* __restrict__ bias,
                                             float* __restrict__ C0)
{
    extern __shared__ float sm[];
    float* As = sm;
    float* Bs = sm + TM * (KD + 1);
    const int tid = threadIdx.x;
    const int m0 = blockIdx.x * TM;
    float* C = C0;
    const float* bg = bias;

    constexpr int NF4 = KD / 4;
    for (int e = tid; e < TM * NF4; e += 256) {
        int q = e % NF4, m = e / NF4;
        float4 v = *reinterpret_cast<const float4*>(&A[(size_t)(m0 + m) * lda + 4 * q]);
        float* dst = &As[m * (KD + 1) + 4 * q];
        dst[0] = v.x; dst[1] = v.y; dst[2] = v.z; dst[3] = v.w;
    }
    for (int e = tid; e < KD * 32; e += 256) {
        int q = e & 31, k = e >> 5;
        float4 v = *reinterpret_cast<const float4*>(&B[(size_t)k * ldb + 4 * q]);
        float* dst = &Bs[k * 129 + 4 * q];
        dst[0] = v.x; dst[1] = v.y; dst[2] = v.z; dst[3] = v.w;
    }
    __syncthreads();

    const int tml = tid & 15;
    const int tnh = tid >> 4;
    constexpr int NR = TM / 16;
    float acc[NR][8] = {};
    #pragma unroll 4
    for (int k = 0; k < KD; ++k) {
        float av[NR], bv[8];
        #pragma unroll
        for (int s = 0; s < NR; ++s) av[s] = As[(tml + 16 * s) * (KD + 1) + k];
        #pragma unroll
        for (int u = 0; u < 8; ++u) bv[u] = Bs[k * 129 + tnh + 16 * u];
        #pragma unroll
        for (int s = 0; s < NR; ++s)
            #pragma unroll
            for (int u = 0; u < 8; ++u) acc[s][u] += av[s] * bv[u];
    }
    __syncthreads();
    float* Ce = sm;
    #pragma unroll
    for (int s = 0; s < NR; ++s)
        #pragma unroll
        for (int u = 0; u < 8; ++u)
            Ce[(tml + 16 * s) * 132 + tnh + 16 * u] = acc[s][u];
    __syncthreads();
    for (int e = tid; e < TM * 32; e += 256) {
        int q = e & 31, m = e >> 5;
        float4 v = *reinterpret_cast<const float4*>(&Ce[m * 132 + 4 * q]);
        float4 b4 = *reinterpret_cast<const float4*>(&bg[4 * q]);
        v.x += b4.x; v.y += b4.y; v.z += b4.z; v.w += b4.w;
        if (DOELU) { v.x = eluf(v.x); v.y = eluf(v.y); v.z = eluf(v.z); v.w = eluf(v.w); }
        *reinterpret_cast<float4*>(&C[(size_t)(m0 + m) * 128 + 4 * q]) = v;
    }
}

// ---------------------------------------------------------------------------
// conv_fused: whole DynamicEdgeConv layer, 2 blocks/graph (rows r0..r0+63).
//  P1: stage X -> Xhi/Xlo bf16 (swizzled) + Sq.
//  P2: waves 0-3: d2 MFMA -> D[64][130]; waves 4-7: c-GEMM (all 128 j, B-frags
//      straight from global wcatT) -> shfl-pair f16x2 pack -> Cc[128][66].
//  P3: all waves: a-GEMM (own 64 rows) + bias -> A_lds (overlays dead Xlo);
//      knn radix-select top-24 -> compacted idx.
//  P4: combine: out = elu(A_lds + max_t Cc[idx]) -> hout.
// LDS: Xhi 32K | Xlo/A_lds 32K | D 33280 | Cc 33792 | idx 6K | Sq 512
//      = 139264 B
// ---------------------------------------------------------------------------
#define XHI_OFF 0
#define XLO_OFF 32768
#define D_OFF   65536
#define CC_OFF  98816
#define IDX_OFF 132608
#define SQ_OFF  138752
#define CONV_LDS 139264

__global__ __launch_bounds__(512) void conv_fused(const float* __restrict__ hin,
                                                  const unsigned short* __restrict__ wT,
                                                  const float* __restrict__ bias,
                                                  float* __restrict__ hout)
{
    extern __shared__ char smc[];
    float* D  = (float*)(smc + D_OFF);                   // [64][130]
    float* Sq = (float*)(smc + SQ_OFF);                  // [128]
    unsigned int* idxL = (unsigned int*)(smc + IDX_OFF); // [64][24]
    unsigned int* Cc   = (unsigned int*)(smc + CC_OFF);  // [128][66]
    float* Al = (float*)(smc + XLO_OFF);                 // [64][128] after d2

    const int g = blockIdx.x >> 1, half = blockIdx.x & 1;
    const int r0 = half * 64;
    const int tid = threadIdx.x;
    const float* hg = hin + (size_t)g * NPTS * FDIM;
    float* og = hout + (size_t)g * NPTS * FDIM;

    // ---- P1: split-stage X + Sq ----
    {
        const int m = tid >> 2;            // row 0..127
        const int k0 = (tid & 3) * 32;
        float sq = 0.f;
        #pragma unroll
        for (int i = 0; i < 8; ++i) {
            float4 v = *reinterpret_cast<const float4*>(&hg[m * 128 + k0 + 4 * i]);
            ushort4 hi, lo;
            hi.x = f2bf(v.x); lo.x = f2bf(v.x - bf2f(hi.x));
            hi.y = f2bf(v.y); lo.y = f2bf(v.y - bf2f(hi.y));
            hi.z = f2bf(v.z); lo.z = f2bf(v.z - bf2f(hi.z));
            hi.w = f2bf(v.w); lo.w = f2bf(v.w - bf2f(hi.w));
            sq += v.x * v.x + v.y * v.y + v.z * v.z + v.w * v.w;
            int byte = (m * 256 + (k0 + 4 * i) * 2) ^ ((m & 15) << 4);
            *reinterpret_cast<ushort4*>(smc + XHI_OFF + byte) = hi;
            *reinterpret_cast<ushort4*>(smc + XLO_OFF + byte) = lo;
        }
        sq += __shfl_xor(sq, 1);
        sq += __shfl_xor(sq, 2);
        if ((tid & 3) == 0) Sq[m] = sq;
    }
    __syncthreads();   // B1

    const int l = tid & 63, w = tid >> 6;
    const int lr = l & 15, lg = l >> 4;

    // ---- P2: d2 (waves 0-3) || c-GEMM (waves 4-7) ----
    if (w < 4) {
        const int arow = r0 + w * 16 + lr;
        const int aswz = (arow & 15) << 4;
        f32x4 acc[8] = {};
        #pragma unroll
        for (int ks = 0; ks < 4; ++ks) {
            int abyte = (arow * 256 + ks * 64 + lg * 16) ^ aswz;
            s8v ahi = *reinterpret_cast<const s8v*>(smc + XHI_OFF + abyte);
            s8v alo = *reinterpret_cast<const s8v*>(smc + XLO_OFF + abyte);
            #pragma unroll
            for (int ni = 0; ni < 8; ++ni) {
                int brow = ni * 16 + lr;
                int bbyte = (brow * 256 + ks * 64 + lg * 16) ^ ((brow & 15) << 4);
                s8v bhi = *reinterpret_cast<const s8v*>(smc + XHI_OFF + bbyte);
                s8v blo = *reinterpret_cast<const s8v*>(smc + XLO_OFF + bbyte);
                acc[ni] = __builtin_amdgcn_mfma_f32_16x16x32_bf16(alo, bhi, acc[ni], 0, 0, 0);
                acc[ni] = __builtin_amdgcn_mfma_f32_16x16x32_bf16(ahi, blo, acc[ni], 0, 0, 0);
                acc[ni] = __builtin_amdgcn_mfma_f32_16x16x32_bf16(ahi, bhi, acc[ni], 0, 0, 0);
            }
        }
        float sqa[4];
        #pragma unroll
        for (int q = 0; q < 4; ++q) sqa[q] = Sq[r0 + w * 16 + lg * 4 + q];
        #pragma unroll
        for (int ni = 0; ni < 8; ++ni) {
            float sqc = Sq[ni * 16 + lr];
            #pragma unroll
            for (int q = 0; q < 4; ++q)
                D[(w * 16 + lg * 4 + q) * 130 + ni * 16 + lr] =
                    sqa[q] + sqc - 2.f * acc[ni][q];
        }
    } else {
        const int w4 = w - 4;
        f32x4 acc[2][8] = {};
        #pragma unroll
        for (int ks = 0; ks < 4; ++ks) {
            s8v a_f[2];
            #pragma unroll
            for (int m2 = 0; m2 < 2; ++m2) {
                int row = (2 * w4 + m2) * 16 + lr;
                int byte = (row * 256 + ks * 64 + lg * 16) ^ ((row & 15) << 4);
                a_f[m2] = *reinterpret_cast<const s8v*>(smc + XHI_OFF + byte);
            }
            #pragma unroll
            for (int ni = 0; ni < 8; ++ni) {
                int n = 128 + ni * 16 + lr;
                s8v b = *reinterpret_cast<const s8v*>(wT + n * 128 + ks * 32 + lg * 8);
                #pragma unroll
                for (int m2 = 0; m2 < 2; ++m2)
                    acc[m2][ni] = __builtin_amdgcn_mfma_f32_16x16x32_bf16(
                        a_f[m2], b, acc[m2][ni], 0, 0, 0);
            }
        }
        // pack f16x2 via lane-pairing, write Cc
        #pragma unroll
        for (int m2 = 0; m2 < 2; ++m2)
            #pragma unroll
            for (int ni = 0; ni < 8; ++ni)
                #pragma unroll
                for (int q = 0; q < 4; ++q) {
                    float v = acc[m2][ni][q];
                    float p = __shfl_xor(v, 1);
                    if (!(lr & 1)) {
                        unsigned int u =
                            ((unsigned int)__half_as_ushort(__float2half(p)) << 16)
                          |  (unsigned int)__half_as_ushort(__float2half(v));
                        int j = (2 * w4 + m2) * 16 + lg * 4 + q;
                        Cc[j * 66 + ni * 8 + (lr >> 1)] = u;
                    }
                }
    }
    __syncthreads();   // B2

    // ---- P3a: a-GEMM (all 8 waves) -> A_lds ----
    {
        const int mt = w >> 1;
        const int nb = (w & 1) * 4;
        f32x4 acc[4] = {};
        const int arow = r0 + mt * 16 + lr;
        const int aswz = (arow & 15) << 4;
        #pragma unroll
        for (int ks = 0; ks < 4; ++ks) {
            int abyte = (arow * 256 + ks * 64 + lg * 16) ^ aswz;
            s8v a_f = *reinterpret_cast<const s8v*>(smc + XHI_OFF + abyte);
            #pragma unroll
            for (int ni = 0; ni < 4; ++ni) {
                int n = (nb + ni) * 16 + lr;
                s8v b = *reinterpret_cast<const s8v*>(wT + n * 128 + ks * 32 + lg * 8);
                acc[ni] = __builtin_amdgcn_mfma_f32_16x16x32_bf16(a_f, b, acc[ni], 0, 0, 0);
            }
        }
        #pragma unroll
        for (int ni = 0; ni < 4; ++ni) {
            int h = (nb + ni) * 16 + lr;
            float bl = bias[h];
            #pragma unroll
            for (int q = 0; q < 4; ++q)
                Al[(mt * 16 + lg * 4 + q) * 128 + h] = acc[ni][q] + bl;
        }
    }

    // ---- P3b: knn radix-select + compact (8 rows per wave) ----
    for (int lr2 = w * 8; lr2 < w * 8 + 8; ++lr2) {
        float2 cur = *reinterpret_cast<const float2*>(&D[lr2 * 130 + 2 * l]);
        unsigned int ub0 = __float_as_uint(cur.x);
        unsigned int ub1 = __float_as_uint(cur.y);
        unsigned int u0 = (ub0 & 0x80000000u) ? ~ub0 : (ub0 | 0x80000000u);
        unsigned int u1 = (ub1 & 0x80000000u) ? ~ub1 : (ub1 | 0x80000000u);

        bool c0 = true, c1 = true, in0 = false, in1 = false;
        int need = KNNK;
        for (int b = 31; b >= 0; --b) {
            bool z0 = c0 && !((u0 >> b) & 1u);
            bool z1 = c1 && !((u1 >> b) & 1u);
            int cnt = __popcll(__ballot(z0)) + __popcll(__ballot(z1));
            if (cnt > need) { c0 = z0; c1 = z1; }
            else if (cnt == need) { in0 |= z0; in1 |= z1; need = 0; break; }
            else { in0 |= z0; in1 |= z1; need -= cnt;
                   c0 = c0 && !z0; c1 = c1 && !z1; }
        }
        if (need > 0) {
            unsigned long long m0 = __ballot(c0), m1 = __ballot(c1);
            unsigned long long below = (1ull << l) - 1ull;
            int rk0 = __popcll(m0 & below) + __popcll(m1 & below);
            int rk1 = rk0 + (int)((m0 >> l) & 1ull);
            in0 = in0 || (c0 && rk0 < need);
            in1 = in1 || (c1 && rk1 < need);
        }
        unsigned long long f0 = __ballot(in0), f1 = __ballot(in1);
        int cnt0 = __popcll(f0);
        unsigned long long below = (1ull << l) - 1ull;
        if (in0) idxL[lr2 * KNNK + __popcll(f0 & below)] = 2 * l;
        if (in1) idxL[lr2 * KNNK + cnt0 + __popcll(f1 & below)] = 2 * l + 1;
    }
    __syncthreads();   // B3

    // ---- P4: combine ----
    {
        const int hh = l >> 5, jl = l & 31;
        #pragma unroll
        for (int u = 0; u < 4; ++u) {
            const int r = w * 8 + 2 * u + hh;
            const unsigned int* il = &idxL[r * KNNK];
            float mc0 = -3.0e38f, mc1 = -3.0e38f, mc2 = -3.0e38f, mc3 = -3.0e38f;
            #pragma unroll
            for (int t = 0; t < KNNK; t += 4) {
                unsigned int p0 = il[t], p1 = il[t + 1], p2 = il[t + 2], p3 = il[t + 3];
                uint2 a = *reinterpret_cast<const uint2*>(&Cc[p0 * 66 + 2 * jl]);
                uint2 b = *reinterpret_cast<const uint2*>(&Cc[p1 * 66 + 2 * jl]);
                uint2 c = *reinterpret_cast<const uint2*>(&Cc[p2 * 66 + 2 * jl]);
                uint2 d = *reinterpret_cast<const uint2*>(&Cc[p3 * 66 + 2 * jl]);
                mc0 = fmaxf(fmaxf(mc0,
                        __half2float(__ushort_as_half((unsigned short)(a.x & 0xffffu)))),
                        fmaxf(__half2float(__ushort_as_half((unsigned short)(b.x & 0xffffu))),
                              fmaxf(__half2float(__ushort_as_half((unsigned short)(c.x & 0xffffu))),
                                    __half2float(__ushort_as_half((unsigned short)(d.x & 0xffffu))))));
                mc1 = fmaxf(fmaxf(mc1,
                        __half2float(__ushort_as_half((unsigned short)(a.x >> 16)))),
                        fmaxf(__half2float(__ushort_as_half((unsigned short)(b.x >> 16))),
                              fmaxf(__half2float(__ushort_as_half((unsigned short)(c.x >> 16))),
                                    __half2float(__ushort_as_half((unsigned short)(d.x >> 16))))));
                mc2 = fmaxf(fmaxf(mc2,
                        __half2float(__ushort_as_half((unsigned short)(a.y & 0xffffu)))),
                        fmaxf(__half2float(__ushort_as_half((unsigned short)(b.y & 0xffffu))),
                              fmaxf(__half2float(__ushort_as_half((unsigned short)(c.y & 0xffffu))),
                                    __half2float(__ushort_as_half((unsigned short)(d.y & 0xffffu))))));
                mc3 = fmaxf(fmaxf(mc3,
                        __half2float(__ushort_as_half((unsigned short)(a.y >> 16)))),
                        fmaxf(__half2float(__ushort_as_half((unsigned short)(b.y >> 16))),
                              fmaxf(__half2float(__ushort_as_half((unsigned short)(c.y >> 16))),
                                    __half2float(__ushort_as_half((unsigned short)(d.y >> 16))))));
            }
            float4 av = *reinterpret_cast<const float4*>(&Al[r * 128 + 4 * jl]);
            float4 o;
            o.x = eluf(av.x + mc0);
            o.y = eluf(av.y + mc1);
            o.z = eluf(av.z + mc2);
            o.w = eluf(av.w + mc3);
            *reinterpret_cast<float4*>(&og[(r0 + r) * 128 + 4 * jl]) = o;
        }
    }
}

// ---------------------------------------------------------------------------
// head: per-graph sum-pool (4-way split, 512 thr) + 128->64->32->32->6 MLP
// ---------------------------------------------------------------------------
__global__ __launch_bounds__(512) void head_kernel(const float* __restrict__ h,
        const float* __restrict__ w1, const float* __restrict__ b1,
        const float* __restrict__ w2, const float* __restrict__ b2,
        const float* __restrict__ w3, const float* __restrict__ b3,
        const float* __restrict__ w4, const float* __restrict__ b4,
        float* __restrict__ out)
{
    __shared__ float ps[4][128];
    __shared__ float pooled[128], s1[64], s2[32], s3[32];
    const int g = blockIdx.x, t = threadIdx.x;
    const float* hg = h + (size_t)g * NPTS * FDIM;
    const int f = t & 127, hp = t >> 7;
    float s = 0.0f;
    for (int p = 0; p < 32; ++p) s += hg[(hp * 32 + p) * 128 + f];
    ps[hp][f] = s;
    __syncthreads();
    if (t < 128) pooled[t] = ps[0][t] + ps[1][t] + ps[2][t] + ps[3][t];
    __syncthreads();
    if (t < 64) {
        float a = b1[t];
        #pragma unroll 8
        for (int k = 0; k < 128; ++k) a += pooled[k] * w1[k * 64 + t];
        s1[t] = eluf(a);
    }
    __syncthreads();
    if (t < 32) {
        float a = b2[t];
        #pragma unroll 8
        for (int k = 0; k < 64; ++k) a += s1[k] * w2[k * 32 + t];
        s2[t] = eluf(a);
    }
    __syncthreads();
    if (t < 32) {
        float a = b3[t];
        #pragma unroll 8
        for (int k = 0; k < 32; ++k) a += s2[k] * w3[k * 32 + t];
        s3[t] = eluf(a);
    }
    __syncthreads();
    if (t < 6) {
        float a = b4[t];
        #pragma unroll 8
        for (int k = 0; k < 32; ++k) a += s3[k] * w4[k * 6 + t];
        out[g * 6 + t] = a;
    }
}

// ---------------------------------------------------------------------------
extern "C" void kernel_launch(void* const* d_in, const int* in_sizes, int n_in,
                              void* d_out, int out_size, void* d_ws, size_t ws_size,
                              hipStream_t stream)
{
    const float* x_pf   = (const float*)d_in[0];
    const float* enc_w1 = (const float*)d_in[1];
    const float* enc_b1 = (const float*)d_in[2];
    const float* enc_w2 = (const float*)d_in[3];
    const float* enc_b2 = (const float*)d_in[4];
    const float* c1w = (const float*)d_in[5];
    const float* c1b = (const float*)d_in[6];
    const float* c2w = (const float*)d_in[7];
    const float* c2b = (const float*)d_in[8];
    const float* c3w = (const float*)d_in[9];
    const float* c3b = (const float*)d_in[10];
    const float* o_w1 = (const float*)d_in[11];
    const float* o_b1 = (const float*)d_in[12];
    const float* o_w2 = (const float*)d_in[13];
    const float* o_b2 = (const float*)d_in[14];
    const float* o_w3 = (const float*)d_in[15];
    const float* o_b3 = (const float*)d_in[16];
    const float* o_w4 = (const float*)d_in[17];
    const float* o_b4 = (const float*)d_in[18];
    const int*   bpf  = (const int*)d_in[19];
    float* out = (float*)d_out;

    float* ws   = (float*)d_ws;
    float* h_a  = ws;                              // 16384*128 f32
    float* h_b  = h_a + (size_t)NTOT * FDIM;       // 16384*128 f32
    float* ac_c = h_b + (size_t)NTOT * FDIM;       // 16384*128 f32 (enc1 out)
    unsigned short* wcatT = (unsigned short*)(ac_c + (size_t)NTOT * FDIM); // 3*256*128 bf16
    unsigned short* enc2T = wcatT + 3 * 32768;     // 128*128 bf16
    float* biasF = (float*)(enc2T + 16384);        // 3*256 f32

    prep_kernel<<<451, 256, 0, stream>>>(c1w, c2w, c3w, enc_w2,
                                         c1b, c2b, c3b, wcatT, enc2T, biasF,
                                         bpf, out);

    // encoder
    gemm2<16, 64, 1><<<dim3(NTOT / 64, 1), 256, 8448 * 4, stream>>>(
        x_pf, 16, enc_w1, 128, enc_b1, ac_c);
    gemmT<1><<<dim3(NTOT / 128, 1), 256, 65536, stream>>>(
        ac_c, enc2T, enc_b2, h_a);

    float* hc = h_a;
    float* hn = h_b;
    for (int l = 0; l < 3; ++l) {
        conv_fused<<<2 * G_NUM, 512, CONV_LDS, stream>>>(
            hc, wcatT + (size_t)l * 32768, biasF + l * 256, hn);
        float* t = hc; hc = hn; hn = t;
    }

    head_kernel<<<G_NUM, 512, 0, stream>>>(hc, o_w1, o_b1, o_w2, o_b2, o_w3, o_b3,
                                           o_w4, o_b4, out);
}

// Round 6
// 257.949 us; speedup vs baseline: 1.9301x; 1.1340x over previous
//
#include <hip/hip_runtime.h>
#include <hip/hip_fp16.h>
#include <hip/hip_bf16.h>
#include <cmath>

#define G_NUM 128
#define NPTS  128
#define FDIM  128
#define KNNK  24
#define NTOT  (G_NUM*NPTS)   // 16384

typedef short s8v __attribute__((ext_vector_type(8)));   // 8 bf16 (4 VGPRs)
typedef float f32x4 __attribute__((ext_vector_type(4))); // MFMA accumulator

__device__ __forceinline__ float eluf(float x){ return x > 0.0f ? x : expm1f(x); }

__device__ __forceinline__ unsigned short f2bf(float f) {
    unsigned int u = __float_as_uint(f);
    unsigned int r = (u + 0x7fffu + ((u >> 16) & 1u)) >> 16;   // RNE
    return (unsigned short)r;
}
__device__ __forceinline__ float bf2f(unsigned short b) {
    return __uint_as_float(((unsigned int)b) << 16);
}

// ---------------------------------------------------------------------------
// prep: wcatT[l][n][k] bf16 (n<128: Wtop-Wbot col, else Wbot col), enc2T[n][k]
// bf16, bias[l][256] f32 (c-half zero). Also writes batch_pf -> out[768..].
// ---------------------------------------------------------------------------
__global__ void prep_kernel(const float* __restrict__ w1, const float* __restrict__ w2,
                            const float* __restrict__ w3, const float* __restrict__ ew2,
                            const float* __restrict__ b1, const float* __restrict__ b2,
                            const float* __restrict__ b3,
                            unsigned short* __restrict__ wcatT,
                            unsigned short* __restrict__ enc2T,
                            float* __restrict__ bias,
                            const int* __restrict__ bpf,
                            float* __restrict__ out)
{
    int e = blockIdx.x * 256 + threadIdx.x;
    if (e < 16384) out[768 + e] = (float)bpf[e];
    if (e < 98304) {                       // 3 * 128k * 256n
        int l = e >> 15;
        int r = e & 32767;
        int k = r >> 8;                    // 0..127
        int n = r & 255;                   // 0..255
        const float* w = (l == 0) ? w1 : ((l == 1) ? w2 : w3);
        float v = (n < 128) ? (w[k * 128 + n] - w[(128 + k) * 128 + n])
                            : w[(128 + k) * 128 + (n - 128)];
        wcatT[l * 32768 + n * 128 + k] = f2bf(v);
    } else if (e < 114688) {               // enc2T: 128k * 128n
        int i = e - 98304;
        int k = i >> 7, n = i & 127;
        enc2T[n * 128 + k] = f2bf(ew2[k * 128 + n]);
    } else if (e < 115456) {
        int j = e - 114688;
        int l = j >> 8, c = j & 255;
        const float* b = (l == 0) ? b1 : ((l == 1) ? b2 : b3);
        bias[l * 256 + c] = (c < 128) ? b[c] : 0.0f;
    }
}

// ---------------------------------------------------------------------------
// enc_fused: 256 blocks x 512 thr, 64 rows each.
//  stage x(64x16)+W1(16x128) -> enc1 fp32 VALU -> bf16 A (swizzled LDS) ->
//  enc2 MFMA (B from global enc2T) -> elu -> h f32.
// ---------------------------------------------------------------------------
#define E_XS  0        // 64*17 f32   = 4352
#define E_W1  4352     // 2048 f32    = 8192
#define E_A   12544    // 64 rows * 256 B = 16384;  total 28928
__global__ __launch_bounds__(512) void enc_fused(const float* __restrict__ x_pf,
                                                 const float* __restrict__ w1,
                                                 const float* __restrict__ b1,
                                                 const unsigned short* __restrict__ e2T,
                                                 const float* __restrict__ b2,
                                                 float* __restrict__ hout)
{
    __shared__ char smc[28928];
    float* xs  = (float*)(smc + E_XS);
    float* ws1 = (float*)(smc + E_W1);
    const int tid = threadIdx.x;
    const int m0 = blockIdx.x * 64;

    for (int e = tid; e < 1024; e += 512) {
        int m = e >> 4, k = e & 15;
        xs[m * 17 + k] = x_pf[(size_t)(m0 + m) * 16 + k];
    }
    for (int e = tid; e < 2048; e += 512) ws1[e] = w1[e];
    __syncthreads();

    {   // enc1: h1[m][h] = elu(b1[h] + sum_k xs[m][k]*W1[k][h]) -> bf16 A
        const int h = tid & 127, mg = tid >> 7;
        float bb = b1[h];
        #pragma unroll
        for (int i = 0; i < 16; ++i) {
            int m = mg * 16 + i;
            float a = bb;
            #pragma unroll
            for (int k = 0; k < 16; ++k) a += xs[m * 17 + k] * ws1[k * 128 + h];
            a = eluf(a);
            int byte = (m * 256 + h * 2) ^ ((m & 15) << 4);
            *reinterpret_cast<unsigned short*>(smc + E_A + byte) = f2bf(a);
        }
    }
    __syncthreads();

    {   // enc2 MFMA: 8 waves: mt = w>>1 (16-row tile), nh = w&1 (64-col half)
        const int l = tid & 63, w = tid >> 6;
        const int lr = l & 15, lg = l >> 4;
        const int mt = w >> 1, nh = w & 1;
        f32x4 acc[4] = {};
        #pragma unroll
        for (int ks = 0; ks < 4; ++ks) {
            int row = mt * 16 + lr;
            int abyte = (row * 256 + ks * 64 + lg * 16) ^ ((row & 15) << 4);
            s8v a_f = *reinterpret_cast<const s8v*>(smc + E_A + abyte);
            #pragma unroll
            for (int ni = 0; ni < 4; ++ni) {
                int n = nh * 64 + ni * 16 + lr;
                s8v b = *reinterpret_cast<const s8v*>(e2T + n * 128 + ks * 32 + lg * 8);
                acc[ni] = __builtin_amdgcn_mfma_f32_16x16x32_bf16(a_f, b, acc[ni], 0, 0, 0);
            }
        }
        #pragma unroll
        for (int ni = 0; ni < 4; ++ni) {
            int n = nh * 64 + ni * 16 + lr;
            float bl = b2[n];
            #pragma unroll
            for (int q = 0; q < 4; ++q)
                hout[(size_t)(m0 + mt * 16 + lg * 4 + q) * 128 + n] = eluf(acc[ni][q] + bl);
        }
    }
}

// ---------------------------------------------------------------------------
// conv_fused v2: 1024 thr (16 waves, 4/SIMD), 2 blocks/graph (XCD-paired).
//  P1: stage X -> Xhi/Xlo bf16 (swizzled) + Sq (8-lane shfl reduce).
//  P2: waves 0-7: d2 MFMA (split-bf16) -> D[64][130];
//      waves 8-15: c-GEMM (B from global wT) -> f16x2 pack -> Cc[128][66].
//  P3: all 16 waves: a-GEMM -> Al (row-XOR swizzled, overlays Xlo);
//      radix-select top-24 (4 rows/wave) -> compacted idx.
//  P4: combine elu(Al + max Cc[idx]); POOL: partial sum -> ppool, skip og.
// LDS: Xhi 32K | Xlo/Al 32K | D 33280 (pp[32][132] overlays) | Cc 33792 |
//      idx 6144 | Sq 512 = 139264 B
// ---------------------------------------------------------------------------
#define XHI_OFF 0
#define XLO_OFF 32768
#define D_OFF   65536
#define CC_OFF  98816
#define IDX_OFF 132608
#define SQ_OFF  138752
#define CONV_LDS 139264

template<int POOL>
__global__ __launch_bounds__(1024, 4) void conv_fused(const float* __restrict__ hin,
                                                      const unsigned short* __restrict__ wT,
                                                      const float* __restrict__ bias,
                                                      float* __restrict__ hout,
                                                      float* __restrict__ ppool)
{
    extern __shared__ char smc[];
    float* D  = (float*)(smc + D_OFF);                   // [64][130]
    float* pp = (float*)(smc + D_OFF);                   // [32][132] (P4, POOL)
    float* Sq = (float*)(smc + SQ_OFF);                  // [128]
    unsigned int* idxL = (unsigned int*)(smc + IDX_OFF); // [64][24]
    unsigned int* Cc   = (unsigned int*)(smc + CC_OFF);  // [128][66]

    // XCD-pair swizzle: both halves of a graph share blockIdx%8 -> same XCD L2
    const int bid = blockIdx.x;
    const int g  = (bid & 7) * 16 + (bid >> 4);
    const int hf = (bid >> 3) & 1;
    const int r0 = hf * 64;
    const int tid = threadIdx.x;
    const float* hg = hin + (size_t)g * NPTS * FDIM;
    float* og = hout + (size_t)g * NPTS * FDIM;

    // ---- P1: split-stage X + Sq ----
    {
        const int m = tid >> 3;            // row 0..127
        const int k0 = (tid & 7) * 16;
        float sq = 0.f;
        #pragma unroll
        for (int i = 0; i < 4; ++i) {
            float4 v = *reinterpret_cast<const float4*>(&hg[m * 128 + k0 + 4 * i]);
            ushort4 hi, lo;
            hi.x = f2bf(v.x); lo.x = f2bf(v.x - bf2f(hi.x));
            hi.y = f2bf(v.y); lo.y = f2bf(v.y - bf2f(hi.y));
            hi.z = f2bf(v.z); lo.z = f2bf(v.z - bf2f(hi.z));
            hi.w = f2bf(v.w); lo.w = f2bf(v.w - bf2f(hi.w));
            sq += v.x * v.x + v.y * v.y + v.z * v.z + v.w * v.w;
            int byte = (m * 256 + (k0 + 4 * i) * 2) ^ ((m & 15) << 4);
            *reinterpret_cast<ushort4*>(smc + XHI_OFF + byte) = hi;
            *reinterpret_cast<ushort4*>(smc + XLO_OFF + byte) = lo;
        }
        sq += __shfl_xor(sq, 1);
        sq += __shfl_xor(sq, 2);
        sq += __shfl_xor(sq, 4);
        if ((tid & 7) == 0) Sq[m] = sq;
    }
    __syncthreads();   // B1

    const int l = tid & 63, w = tid >> 6;
    const int lr = l & 15, lg = l >> 4;

    // ---- P2: d2 (waves 0-7) || c-GEMM (waves 8-15) ----
    if (w < 8) {
        const int t2 = w >> 1;             // 16-row tile
        const int nh = w & 1;              // col half
        const int arow = r0 + t2 * 16 + lr;
        const int aswz = (arow & 15) << 4;
        f32x4 acc[4] = {};
        #pragma unroll
        for (int ks = 0; ks < 4; ++ks) {
            int abyte = (arow * 256 + ks * 64 + lg * 16) ^ aswz;
            s8v ahi = *reinterpret_cast<const s8v*>(smc + XHI_OFF + abyte);
            s8v alo = *reinterpret_cast<const s8v*>(smc + XLO_OFF + abyte);
            #pragma unroll
            for (int ni = 0; ni < 4; ++ni) {
                int brow = (nh * 4 + ni) * 16 + lr;
                int bbyte = (brow * 256 + ks * 64 + lg * 16) ^ ((brow & 15) << 4);
                s8v bhi = *reinterpret_cast<const s8v*>(smc + XHI_OFF + bbyte);
                s8v blo = *reinterpret_cast<const s8v*>(smc + XLO_OFF + bbyte);
                acc[ni] = __builtin_amdgcn_mfma_f32_16x16x32_bf16(alo, bhi, acc[ni], 0, 0, 0);
                acc[ni] = __builtin_amdgcn_mfma_f32_16x16x32_bf16(ahi, blo, acc[ni], 0, 0, 0);
                acc[ni] = __builtin_amdgcn_mfma_f32_16x16x32_bf16(ahi, bhi, acc[ni], 0, 0, 0);
            }
        }
        float sqa[4];
        #pragma unroll
        for (int q = 0; q < 4; ++q) sqa[q] = Sq[r0 + t2 * 16 + lg * 4 + q];
        #pragma unroll
        for (int ni = 0; ni < 4; ++ni) {
            int col = (nh * 4 + ni) * 16 + lr;
            float sqc = Sq[col];
            #pragma unroll
            for (int q = 0; q < 4; ++q)
                D[(t2 * 16 + lg * 4 + q) * 130 + col] = sqa[q] + sqc - 2.f * acc[ni][q];
        }
    } else {
        const int jt = w - 8;              // j-tile (16 rows each, 8 tiles)
        f32x4 acc[8] = {};
        #pragma unroll
        for (int ks = 0; ks < 4; ++ks) {
            int row = jt * 16 + lr;
            int byte = (row * 256 + ks * 64 + lg * 16) ^ ((row & 15) << 4);
            s8v a_f = *reinterpret_cast<const s8v*>(smc + XHI_OFF + byte);
            #pragma unroll
            for (int ni = 0; ni < 8; ++ni) {
                int n = 128 + ni * 16 + lr;
                s8v b = *reinterpret_cast<const s8v*>(wT + n * 128 + ks * 32 + lg * 8);
                acc[ni] = __builtin_amdgcn_mfma_f32_16x16x32_bf16(a_f, b, acc[ni], 0, 0, 0);
            }
        }
        #pragma unroll
        for (int ni = 0; ni < 8; ++ni)
            #pragma unroll
            for (int q = 0; q < 4; ++q) {
                float v = acc[ni][q];
                float p = __shfl_xor(v, 1);
                if (!(lr & 1)) {
                    unsigned int u =
                        ((unsigned int)__half_as_ushort(__float2half(p)) << 16)
                      |  (unsigned int)__half_as_ushort(__float2half(v));
                    int j = jt * 16 + lg * 4 + q;
                    Cc[j * 66 + ni * 8 + (lr >> 1)] = u;
                }
            }
    }
    __syncthreads();   // B2

    // ---- P3a: a-GEMM (16 waves) -> Al (XOR-swizzled, overlays Xlo) ----
    {
        const int mt = w >> 2;             // 0..3
        const int nb = (w & 3) * 2;        // 0,2,4,6
        const int arow = r0 + mt * 16 + lr;
        const int aswz = (arow & 15) << 4;
        f32x4 acc[2] = {};
        #pragma unroll
        for (int ks = 0; ks < 4; ++ks) {
            int abyte = (arow * 256 + ks * 64 + lg * 16) ^ aswz;
            s8v a_f = *reinterpret_cast<const s8v*>(smc + XHI_OFF + abyte);
            #pragma unroll
            for (int ni = 0; ni < 2; ++ni) {
                int n = (nb + ni) * 16 + lr;
                s8v b = *reinterpret_cast<const s8v*>(wT + n * 128 + ks * 32 + lg * 8);
                acc[ni] = __builtin_amdgcn_mfma_f32_16x16x32_bf16(a_f, b, acc[ni], 0, 0, 0);
            }
        }
        #pragma unroll
        for (int ni = 0; ni < 2; ++ni) {
            int h = (nb + ni) * 16 + lr;
            float bl = bias[h];
            #pragma unroll
            for (int q = 0; q < 4; ++q) {
                int row = mt * 16 + lg * 4 + q;
                int byte = (row * 512 + h * 4) ^ ((row & 3) << 4);
                *reinterpret_cast<float*>(smc + XLO_OFF + byte) = acc[ni][q] + bl;
            }
        }
    }

    // ---- P3b: knn radix-select + compact (4 rows/wave) ----
    for (int lr2 = w * 4; lr2 < w * 4 + 4; ++lr2) {
        float2 cur = *reinterpret_cast<const float2*>(&D[lr2 * 130 + 2 * l]);
        unsigned int ub0 = __float_as_uint(cur.x);
        unsigned int ub1 = __float_as_uint(cur.y);
        unsigned int u0 = (ub0 & 0x80000000u) ? ~ub0 : (ub0 | 0x80000000u);
        unsigned int u1 = (ub1 & 0x80000000u) ? ~ub1 : (ub1 | 0x80000000u);

        bool c0 = true, c1 = true, in0 = false, in1 = false;
        int need = KNNK;
        for (int b = 31; b >= 0; --b) {
            bool z0 = c0 && !((u0 >> b) & 1u);
            bool z1 = c1 && !((u1 >> b) & 1u);
            int cnt = __popcll(__ballot(z0)) + __popcll(__ballot(z1));
            if (cnt > need) { c0 = z0; c1 = z1; }
            else if (cnt == need) { in0 |= z0; in1 |= z1; need = 0; break; }
            else { in0 |= z0; in1 |= z1; need -= cnt;
                   c0 = c0 && !z0; c1 = c1 && !z1; }
        }
        if (need > 0) {
            unsigned long long m0 = __ballot(c0), m1 = __ballot(c1);
            unsigned long long below = (1ull << l) - 1ull;
            int rk0 = __popcll(m0 & below) + __popcll(m1 & below);
            int rk1 = rk0 + (int)((m0 >> l) & 1ull);
            in0 = in0 || (c0 && rk0 < need);
            in1 = in1 || (c1 && rk1 < need);
        }
        unsigned long long f0 = __ballot(in0), f1 = __ballot(in1);
        int cnt0 = __popcll(f0);
        unsigned long long below = (1ull << l) - 1ull;
        if (in0) idxL[lr2 * KNNK + __popcll(f0 & below)] = 2 * l;
        if (in1) idxL[lr2 * KNNK + cnt0 + __popcll(f1 & below)] = 2 * l + 1;
    }
    __syncthreads();   // B3

    // ---- P4: combine (+ optional pooled partial) ----
    {
        const int hh = l >> 5, jl = l & 31;
        float4 ps = {0.f, 0.f, 0.f, 0.f};
        #pragma unroll
        for (int u = 0; u < 2; ++u) {
            const int r = w * 4 + 2 * u + hh;
            const unsigned int* il = &idxL[r * KNNK];
            float mc0 = -3.0e38f, mc1 = -3.0e38f, mc2 = -3.0e38f, mc3 = -3.0e38f;
            #pragma unroll
            for (int t = 0; t < KNNK; t += 4) {
                unsigned int p0 = il[t], p1 = il[t + 1], p2 = il[t + 2], p3 = il[t + 3];
                uint2 a = *reinterpret_cast<const uint2*>(&Cc[p0 * 66 + 2 * jl]);
                uint2 b = *reinterpret_cast<const uint2*>(&Cc[p1 * 66 + 2 * jl]);
                uint2 c = *reinterpret_cast<const uint2*>(&Cc[p2 * 66 + 2 * jl]);
                uint2 d = *reinterpret_cast<const uint2*>(&Cc[p3 * 66 + 2 * jl]);
                mc0 = fmaxf(fmaxf(mc0,
                        __half2float(__ushort_as_half((unsigned short)(a.x & 0xffffu)))),
                        fmaxf(__half2float(__ushort_as_half((unsigned short)(b.x & 0xffffu))),
                              fmaxf(__half2float(__ushort_as_half((unsigned short)(c.x & 0xffffu))),
                                    __half2float(__ushort_as_half((unsigned short)(d.x & 0xffffu))))));
                mc1 = fmaxf(fmaxf(mc1,
                        __half2float(__ushort_as_half((unsigned short)(a.x >> 16)))),
                        fmaxf(__half2float(__ushort_as_half((unsigned short)(b.x >> 16))),
                              fmaxf(__half2float(__ushort_as_half((unsigned short)(c.x >> 16))),
                                    __half2float(__ushort_as_half((unsigned short)(d.x >> 16))))));
                mc2 = fmaxf(fmaxf(mc2,
                        __half2float(__ushort_as_half((unsigned short)(a.y & 0xffffu)))),
                        fmaxf(__half2float(__ushort_as_half((unsigned short)(b.y & 0xffffu))),
                              fmaxf(__half2float(__ushort_as_half((unsigned short)(c.y & 0xffffu))),
                                    __half2float(__ushort_as_half((unsigned short)(d.y & 0xffffu))))));
                mc3 = fmaxf(fmaxf(mc3,
                        __half2float(__ushort_as_half((unsigned short)(a.y >> 16)))),
                        fmaxf(__half2float(__ushort_as_half((unsigned short)(b.y >> 16))),
                              fmaxf(__half2float(__ushort_as_half((unsigned short)(c.y >> 16))),
                                    __half2float(__ushort_as_half((unsigned short)(d.y >> 16))))));
            }
            int abyte = (r * 512 + 16 * jl) ^ ((r & 3) << 4);
            float4 av = *reinterpret_cast<const float4*>(smc + XLO_OFF + abyte);
            float4 o;
            o.x = eluf(av.x + mc0);
            o.y = eluf(av.y + mc1);
            o.z = eluf(av.z + mc2);
            o.w = eluf(av.w + mc3);
            if (!POOL) {
                *reinterpret_cast<float4*>(&og[(r0 + r) * 128 + 4 * jl]) = o;
            } else {
                ps.x += o.x; ps.y += o.y; ps.z += o.z; ps.w += o.w;
            }
        }
        if (POOL) {
            *reinterpret_cast<float4*>(&pp[(w * 2 + hh) * 132 + 4 * jl]) = ps;
            __syncthreads();
            if (tid < 128) {
                float s = 0.f;
                #pragma unroll 8
                for (int rg = 0; rg < 32; ++rg) s += pp[rg * 132 + tid];
                ppool[(g * 2 + hf) * 128 + tid] = s;
            }
        }
    }
}

// ---------------------------------------------------------------------------
// head: reads pooled partials (2 per graph) + 128->64->32->32->6 MLP
// ---------------------------------------------------------------------------
__global__ __launch_bounds__(128) void head_kernel(const float* __restrict__ ppool,
        const float* __restrict__ w1, const float* __restrict__ b1,
        const float* __restrict__ w2, const float* __restrict__ b2,
        const float* __restrict__ w3, const float* __restrict__ b3,
        const float* __restrict__ w4, const float* __restrict__ b4,
        float* __restrict__ out)
{
    __shared__ float pooled[128], s1[64], s2[32], s3[32];
    const int g = blockIdx.x, t = threadIdx.x;
    pooled[t] = ppool[(2 * g) * 128 + t] + ppool[(2 * g + 1) * 128 + t];
    __syncthreads();
    if (t < 64) {
        float a = b1[t];
        #pragma unroll 8
        for (int k = 0; k < 128; ++k) a += pooled[k] * w1[k * 64 + t];
        s1[t] = eluf(a);
    }
    __syncthreads();
    if (t < 32) {
        float a = b2[t];
        #pragma unroll 8
        for (int k = 0; k < 64; ++k) a += s1[k] * w2[k * 32 + t];
        s2[t] = eluf(a);
    }
    __syncthreads();
    if (t < 32) {
        float a = b3[t];
        #pragma unroll 8
        for (int k = 0; k < 32; ++k) a += s2[k] * w3[k * 32 + t];
        s3[t] = eluf(a);
    }
    __syncthreads();
    if (t < 6) {
        float a = b4[t];
        #pragma unroll 8
        for (int k = 0; k < 32; ++k) a += s3[k] * w4[k * 6 + t];
        out[g * 6 + t] = a;
    }
}

// ---------------------------------------------------------------------------
extern "C" void kernel_launch(void* const* d_in, const int* in_sizes, int n_in,
                              void* d_out, int out_size, void* d_ws, size_t ws_size,
                              hipStream_t stream)
{
    const float* x_pf   = (const float*)d_in[0];
    const float* enc_w1 = (const float*)d_in[1];
    const float* enc_b1 = (const float*)d_in[2];
    const float* enc_w2 = (const float*)d_in[3];
    const float* enc_b2 = (const float*)d_in[4];
    const float* c1w = (const float*)d_in[5];
    const float* c1b = (const float*)d_in[6];
    const float* c2w = (const float*)d_in[7];
    const float* c2b = (const float*)d_in[8];
    const float* c3w = (const float*)d_in[9];
    const float* c3b = (const float*)d_in[10];
    const float* o_w1 = (const float*)d_in[11];
    const float* o_b1 = (const float*)d_in[12];
    const float* o_w2 = (const float*)d_in[13];
    const float* o_b2 = (const float*)d_in[14];
    const float* o_w3 = (const float*)d_in[15];
    const float* o_b3 = (const float*)d_in[16];
    const float* o_w4 = (const float*)d_in[17];
    const float* o_b4 = (const float*)d_in[18];
    const int*   bpf  = (const int*)d_in[19];
    float* out = (float*)d_out;

    float* ws   = (float*)d_ws;
    float* h_a  = ws;                              // 16384*128 f32
    float* h_b  = h_a + (size_t)NTOT * FDIM;       // 16384*128 f32
    float* ppool = h_b + (size_t)NTOT * FDIM;      // 256*128 f32
    unsigned short* wcatT = (unsigned short*)(ppool + 256 * 128); // 3*256*128 bf16
    unsigned short* enc2T = wcatT + 3 * 32768;     // 128*128 bf16
    float* biasF = (float*)(enc2T + 16384);        // 3*256 f32

    prep_kernel<<<451, 256, 0, stream>>>(c1w, c2w, c3w, enc_w2,
                                         c1b, c2b, c3b, wcatT, enc2T, biasF,
                                         bpf, out);

    enc_fused<<<NTOT / 64, 512, 0, stream>>>(x_pf, enc_w1, enc_b1,
                                             enc2T, enc_b2, h_a);

    conv_fused<0><<<2 * G_NUM, 1024, CONV_LDS, stream>>>(
        h_a, wcatT, biasF, h_b, ppool);
    conv_fused<0><<<2 * G_NUM, 1024, CONV_LDS, stream>>>(
        h_b, wcatT + 32768, biasF + 256, h_a, ppool);
    conv_fused<1><<<2 * G_NUM, 1024, CONV_LDS, stream>>>(
        h_a, wcatT + 65536, biasF + 512, h_b, ppool);

    head_kernel<<<G_NUM, 128, 0, stream>>>(ppool, o_w1, o_b1, o_w2, o_b2,
                                           o_w3, o_b3, o_w4, o_b4, out);
}